// Round 20
// baseline (171.571 us; speedup 1.0000x reference)
//
#include <hip/hip_runtime.h>
#include <hip/hip_bf16.h>
#include <math.h>

#define BB 16
#define TT 2048
#define DD 1024
#define HH 64
#define QK_SCALE 0.18033688011112042f  // 0.125 * log2(e)  (exp2-domain softmax)
#define ATTN_REP 4  // DIAGNOSTIC: lift attn above the 75us fill rows. Revert.

typedef short bf16x8 __attribute__((ext_vector_type(8)));
typedef short bf16x4 __attribute__((ext_vector_type(4)));
typedef float f32x4 __attribute__((ext_vector_type(4)));

__device__ __forceinline__ short f2bf(float f) {  // RNE (cold paths only)
  union { float f; unsigned u; } c; c.f = f;
  unsigned u = c.u + 0x7FFFu + ((c.u >> 16) & 1u);
  return (short)(u >> 16);
}

// packed pair f32x2 -> bf16x2 (v_cvt_pk_bf16_f32 via standard cast API)
__device__ __forceinline__ unsigned pk2(float lo, float hi) {
  float2 t; t.x = lo; t.y = hi;
  __hip_bfloat162 h = __float22bfloat162_rn(t);
  union { __hip_bfloat162 h; unsigned u; } c; c.h = h;
  return c.u;
}

// Counted-vmcnt fences (T4)
#define FENCE_VM(N)                                        \
  do {                                                     \
    asm volatile("s_waitcnt vmcnt(" #N ")" ::: "memory");  \
    __builtin_amdgcn_sched_barrier(0);                     \
    __builtin_amdgcn_s_barrier();                          \
  } while (0)

// 64-col bf16 tile (128B row stride): XOR-swizzle 16B units by row&7.
__device__ __forceinline__ void* lds_swz(void* base, int row, int col) {
  int byte = (row << 7) + (col << 1);
  byte ^= (row & 7) << 4;
  return (void*)((char*)base + byte);
}

// ---------------------------------------------------------------------------
// Pack Wq|Wk|Wv (fp32 [D][H]) -> Wt bf16 [192][1024]
// ---------------------------------------------------------------------------
__global__ __launch_bounds__(256) void pack_wt(
    const float* __restrict__ Wq, const float* __restrict__ Wk,
    const float* __restrict__ Wv, short* __restrict__ wt) {
  const int idx = blockIdx.x * 256 + threadIdx.x;
  const int n = idx >> 7;
  const int k0 = (idx & 127) << 3;
  const float* W = (n < 64) ? Wq : (n < 128) ? Wk : Wv;
  const int h = n & 63;
  bf16x8 o;
#pragma unroll
  for (int j = 0; j < 8; ++j) o[j] = f2bf(W[(k0 + j) * HH + h]);
  *(bf16x8*)&wt[n * DD + k0] = o;
}

// ---------------------------------------------------------------------------
// QKV GEMM v9 (round-18 best, reps removed).
// ---------------------------------------------------------------------------
__global__ __launch_bounds__(256, 2) void qkv_mfma(
    const float* __restrict__ x, const short* __restrict__ wt,
    short* __restrict__ qo, short* __restrict__ ko, short* __restrict__ vt) {
  __shared__ float xls[4][64 * 64];  // 4 x 16 KB fp32 tiles (64 KB)
  const int tid = threadIdx.x;
  const int lane = tid & 63;
  const int w = tid >> 6;
  const int q16 = lane & 15;
  const int g = lane >> 4;
  const size_t r0 = (size_t)blockIdx.x * 64;

  f32x4 acc[4][3];
#pragma unroll
  for (int mf = 0; mf < 4; ++mf)
#pragma unroll
    for (int nf = 0; nf < 3; ++nf) acc[mf][nf] = (f32x4){0.f, 0.f, 0.f, 0.f};

  const short* wp[3];
#pragma unroll
  for (int nf = 0; nf < 3; ++nf)
    wp[nf] = wt + (size_t)(w * 48 + nf * 16 + q16) * DD + g * 8;

  const int srow_b = w * 16 + (lane >> 4);  // row for j=0; j adds 4
  const int ul = lane & 15;                 // linear 16B-unit within row

  bf16x8 bcur[3][2];
#pragma unroll
  for (int nf = 0; nf < 3; ++nf)
#pragma unroll
    for (int kf = 0; kf < 2; ++kf)
      bcur[nf][kf] = *(const bf16x8*)(wp[nf] + kf * 32);
#pragma unroll
  for (int t = 0; t < 3; ++t)
#pragma unroll
    for (int j = 0; j < 4; ++j) {
      const int row = srow_b + j * 4;
      const int us = ul ^ (row & 7);
      const float* src = x + (r0 + row) * DD + t * 64 + us * 4;
      __builtin_amdgcn_global_load_lds(
          (const __attribute__((address_space(1))) void*)src,
          (__attribute__((address_space(3))) void*)(&xls[t][0] + (w * 4 + j) * 256),
          16, 0, 0);
    }
  __builtin_amdgcn_sched_barrier(0);
  FENCE_VM(8);

  for (int ks = 0; ks < 16; ++ks) {
    const float* bufc = &xls[ks & 3][0];

    bf16x8 bnxt[3][2];
    if (ks < 15) {
      const int k1 = (ks + 1) << 6;
#pragma unroll
      for (int nf = 0; nf < 3; ++nf)
#pragma unroll
        for (int kf = 0; kf < 2; ++kf)
          bnxt[nf][kf] = *(const bf16x8*)(wp[nf] + k1 + kf * 32);
    }
    if (ks <= 12) {
#pragma unroll
      for (int j = 0; j < 4; ++j) {
        const int row = srow_b + j * 4;
        const int us = ul ^ (row & 7);
        const float* src = x + (r0 + row) * DD + (ks + 3) * 64 + us * 4;
        __builtin_amdgcn_global_load_lds(
            (const __attribute__((address_space(1))) void*)src,
            (__attribute__((address_space(3))) void*)(&xls[(ks + 3) & 3][0] +
                                                      (w * 4 + j) * 256),
            16, 0, 0);
      }
    }
    __builtin_amdgcn_sched_barrier(0);

    bf16x8 afr[4][2];
#pragma unroll
    for (int mf = 0; mf < 4; ++mf)
#pragma unroll
      for (int kf = 0; kf < 2; ++kf) {
        const int R = mf * 16 + q16;
        const int r7 = R & 7;
        const int u0 = kf * 8 + g * 2;
        const float4 fa = *(const float4*)(bufc + R * 64 + ((u0 ^ r7) << 2));
        const float4 fb = *(const float4*)(bufc + R * 64 + (((u0 + 1) ^ r7) << 2));
        unsigned* up = (unsigned*)&afr[mf][kf];
        up[0] = pk2(fa.x, fa.y);
        up[1] = pk2(fa.z, fa.w);
        up[2] = pk2(fb.x, fb.y);
        up[3] = pk2(fb.z, fb.w);
      }

#pragma unroll
    for (int mf = 0; mf < 4; ++mf)
#pragma unroll
      for (int nf = 0; nf < 3; ++nf)
#pragma unroll
        for (int kf = 0; kf < 2; ++kf)
          acc[mf][nf] = __builtin_amdgcn_mfma_f32_16x16x32_bf16(
              afr[mf][kf], bcur[nf][kf], acc[mf][nf], 0, 0, 0);

    if (ks < 15) {
      if (ks <= 12) FENCE_VM(14);
      else if (ks == 13) FENCE_VM(10);
      else FENCE_VM(6);
#pragma unroll
      for (int nf = 0; nf < 3; ++nf)
#pragma unroll
        for (int kf = 0; kf < 2; ++kf) bcur[nf][kf] = bnxt[nf][kf];
    }
  }

#pragma unroll
  for (int nf = 0; nf < 3; ++nf) {
    const int n = w * 48 + nf * 16 + q16;
    const int mat = n >> 6;
    const int h = n & 63;
    if (mat < 2) {
      short* outp = mat ? ko : qo;
      const float fac = mat ? 1.0f : QK_SCALE;
#pragma unroll
      for (int mf = 0; mf < 4; ++mf)
#pragma unroll
        for (int r = 0; r < 4; ++r)
          outp[(r0 + mf * 16 + g * 4 + r) * HH + h] = f2bf(acc[mf][nf][r] * fac);
    } else {
      const int bb = (int)(r0 >> 11);
      const int tloc = (int)(r0 & 2047);
#pragma unroll
      for (int mf = 0; mf < 4; ++mf) {
        uint2 pkv;
        pkv.x = pk2(acc[mf][nf][0], acc[mf][nf][1]);
        pkv.y = pk2(acc[mf][nf][2], acc[mf][nf][3]);
        *(uint2*)&vt[((size_t)bb * HH + h) * TT + tloc + mf * 16 + g * 4] = pkv;
      }
    }
  }
}

// ---------------------------------------------------------------------------
// Flash attention (round-10/18 structure) with ATTN_REP internal repeats.
// ---------------------------------------------------------------------------
__global__ __launch_bounds__(256, 4) void attn_mfma(
    const short* __restrict__ q, const short* __restrict__ k,
    const short* __restrict__ vt, float* __restrict__ out) {
  __shared__ short klds[2][64 * 64];
  __shared__ short vlds[2][64 * 64];

  const int id = blockIdx.x;  // 0..511
  const int b = (id & 7) | (((id >> 3) & 1) << 3);
  const int kk = id >> 4;
  const int qt = (kk < 16) ? (31 - kk) : (kk - 16);
  const int t0 = qt << 6;
  const int tid = threadIdx.x;
  const int lane = tid & 63;
  const int w = tid >> 6;
  const int q16 = lane & 15;
  const int g = lane >> 4;
  const int NC = qt + 1;

  const size_t brow = (size_t)b * TT;
  const short* kg = k + brow * HH;
  const short* vtg = vt + (size_t)b * HH * TT;

  const int srow = tid >> 2;
  const int scol = (tid & 3) << 4;

  const int vgA = (scol >> 3) & 3;
  const int vgB = ((scol + 8) >> 3) & 3;
  const int vm2 = scol >> 5;
  const short* vrow_p = vtg + srow * TT + vm2 * 32;

  const bf16x8 ones = {0x3F80, 0x3F80, 0x3F80, 0x3F80,
                       0x3F80, 0x3F80, 0x3F80, 0x3F80};

  for (int rep = 0; rep < ATTN_REP; ++rep) {
    __syncthreads();  // isolate LDS reuse across reps

    bf16x8 kr0 = *(const bf16x8*)&kg[srow * HH + scol];
    bf16x8 kr1 = *(const bf16x8*)&kg[srow * HH + scol + 8];
    bf16x4 va0 = *(const bf16x4*)(vrow_p + 4 * vgA);
    bf16x4 va1 = *(const bf16x4*)(vrow_p + 16 + 4 * vgA);
    bf16x4 vb0 = *(const bf16x4*)(vrow_p + 4 * vgB);
    bf16x4 vb1 = *(const bf16x4*)(vrow_p + 16 + 4 * vgB);

    {
      const short* qsrc = q + (brow + t0 + srow) * HH;
      *(bf16x8*)lds_swz(klds[0], srow, scol) = *(const bf16x8*)&qsrc[scol];
      *(bf16x8*)lds_swz(klds[0], srow, scol + 8) = *(const bf16x8*)&qsrc[scol + 8];
    }
    __syncthreads();
    bf16x8 qa[2];
#pragma unroll
    for (int kf = 0; kf < 2; ++kf)
      qa[kf] = *(bf16x8*)lds_swz(klds[0], w * 16 + q16, kf * 32 + g * 8);
    __syncthreads();

    *(bf16x8*)lds_swz(klds[0], srow, scol) = kr0;
    *(bf16x8*)lds_swz(klds[0], srow, scol + 8) = kr1;
    *(bf16x8*)lds_swz(vlds[0], srow, scol) =
        __builtin_shufflevector(va0, va1, 0, 1, 2, 3, 4, 5, 6, 7);
    *(bf16x8*)lds_swz(vlds[0], srow, scol + 8) =
        __builtin_shufflevector(vb0, vb1, 0, 1, 2, 3, 4, 5, 6, 7);
    __syncthreads();

    f32x4 po[4];
    f32x4 lacc = (f32x4){0.f, 0.f, 0.f, 0.f};
    float m = -INFINITY;
#pragma unroll
    for (int nf = 0; nf < 4; ++nf) po[nf] = (f32x4){0.f, 0.f, 0.f, 0.f};

    int cur = 0;

    for (int c = 0; c < NC; ++c) {
      const bool notlast = (c + 1 < NC);
      if (notlast) {
        const int s1 = (c + 1) << 6;
        kr0 = *(const bf16x8*)&kg[(s1 + srow) * HH + scol];
        kr1 = *(const bf16x8*)&kg[(s1 + srow) * HH + scol + 8];
        va0 = *(const bf16x4*)(vrow_p + s1 + 4 * vgA);
        va1 = *(const bf16x4*)(vrow_p + s1 + 16 + 4 * vgA);
        vb0 = *(const bf16x4*)(vrow_p + s1 + 4 * vgB);
        vb1 = *(const bf16x4*)(vrow_p + s1 + 16 + 4 * vgB);
      }

      f32x4 sfr[4];
#pragma unroll
      for (int nf = 0; nf < 4; ++nf) sfr[nf] = (f32x4){0.f, 0.f, 0.f, 0.f};
      __builtin_amdgcn_s_setprio(1);
#pragma unroll
      for (int nf = 0; nf < 4; ++nf)
#pragma unroll
        for (int kf = 0; kf < 2; ++kf) {
          bf16x8 kb = *(bf16x8*)lds_swz(klds[cur], nf * 16 + q16, kf * 32 + g * 8);
          sfr[nf] = __builtin_amdgcn_mfma_f32_16x16x32_bf16(kb, qa[kf], sfr[nf], 0, 0, 0);
        }
      __builtin_amdgcn_s_setprio(0);

      if (c == NC - 1) {
        const int qloc = w * 16 + q16;
#pragma unroll
        for (int nf = 0; nf < 4; ++nf)
#pragma unroll
          for (int r = 0; r < 4; ++r)
            if (16 * nf + 4 * g + r > qloc) sfr[nf][r] = -INFINITY;
      }

      float pm;
      {
        f32x4 t01 = (f32x4){fmaxf(sfr[0][0], sfr[1][0]), fmaxf(sfr[0][1], sfr[1][1]),
                            fmaxf(sfr[0][2], sfr[1][2]), fmaxf(sfr[0][3], sfr[1][3])};
        f32x4 t23 = (f32x4){fmaxf(sfr[2][0], sfr[3][0]), fmaxf(sfr[2][1], sfr[3][1]),
                            fmaxf(sfr[2][2], sfr[3][2]), fmaxf(sfr[2][3], sfr[3][3])};
        pm = fmaxf(fmaxf(fmaxf(t01[0], t23[0]), fmaxf(t01[1], t23[1])),
                   fmaxf(fmaxf(t01[2], t23[2]), fmaxf(t01[3], t23[3])));
        pm = fmaxf(pm, __shfl_xor(pm, 16));
        pm = fmaxf(pm, __shfl_xor(pm, 32));
      }

      if (__any(pm - m > 8.f)) {
        const float mn = fmaxf(m, pm);
        const float corr = exp2f(m - mn);
        m = mn;
        const int sbase = (lane & 48) + ((lane >> 4) << 2);
#pragma unroll
        for (int r = 0; r < 4; ++r) {
          const float cr = __shfl(corr, sbase + r);
          lacc[r] *= cr;
#pragma unroll
          for (int nf = 0; nf < 4; ++nf) po[nf][r] *= cr;
        }
      }

      bf16x8 pa[2];
#pragma unroll
      for (int m2 = 0; m2 < 2; ++m2) {
        float e0 = exp2f(sfr[2 * m2][0] - m), e1 = exp2f(sfr[2 * m2][1] - m);
        float e2 = exp2f(sfr[2 * m2][2] - m), e3 = exp2f(sfr[2 * m2][3] - m);
        float e4 = exp2f(sfr[2 * m2 + 1][0] - m), e5 = exp2f(sfr[2 * m2 + 1][1] - m);
        float e6 = exp2f(sfr[2 * m2 + 1][2] - m), e7 = exp2f(sfr[2 * m2 + 1][3] - m);
        unsigned* up = (unsigned*)&pa[m2];
        up[0] = pk2(e0, e1); up[1] = pk2(e2, e3);
        up[2] = pk2(e4, e5); up[3] = pk2(e6, e7);
      }

      __builtin_amdgcn_s_setprio(1);
#pragma unroll
      for (int m2 = 0; m2 < 2; ++m2) {
#pragma unroll
        for (int nf = 0; nf < 4; ++nf) {
          bf16x8 vb = *(bf16x8*)lds_swz(vlds[cur], nf * 16 + q16, m2 * 32 + g * 8);
          po[nf] = __builtin_amdgcn_mfma_f32_16x16x32_bf16(pa[m2], vb, po[nf], 0, 0, 0);
        }
        lacc = __builtin_amdgcn_mfma_f32_16x16x32_bf16(pa[m2], ones, lacc, 0, 0, 0);
      }
      __builtin_amdgcn_s_setprio(0);

      if (notlast) {
        *(bf16x8*)lds_swz(klds[cur ^ 1], srow, scol) = kr0;
        *(bf16x8*)lds_swz(klds[cur ^ 1], srow, scol + 8) = kr1;
        *(bf16x8*)lds_swz(vlds[cur ^ 1], srow, scol) =
            __builtin_shufflevector(va0, va1, 0, 1, 2, 3, 4, 5, 6, 7);
        *(bf16x8*)lds_swz(vlds[cur ^ 1], srow, scol + 8) =
            __builtin_shufflevector(vb0, vb1, 0, 1, 2, 3, 4, 5, 6, 7);
        __syncthreads();
        cur ^= 1;
      }
    }

    const int qrow = t0 + w * 16 + g * 4;
#pragma unroll
    for (int nf = 0; nf < 4; ++nf) {
      const int h = nf * 16 + q16;
#pragma unroll
      for (int r = 0; r < 4; ++r)
        out[(brow + qrow + r) * HH + h] = po[nf][r] / lacc[r];
    }
  }
}

extern "C" void kernel_launch(void* const* d_in, const int* in_sizes, int n_in,
                              void* d_out, int out_size, void* d_ws, size_t ws_size,
                              hipStream_t stream) {
  const float* x  = (const float*)d_in[0];
  const float* Wq = (const float*)d_in[1];
  const float* Wk = (const float*)d_in[2];
  const float* Wv = (const float*)d_in[3];
  float* out = (float*)d_out;

  const size_t bth = (size_t)BB * TT * HH;  // 2,097,152
  short* qb  = (short*)d_ws;
  short* kb  = qb + bth;
  short* vtb = kb + bth;
  short* wtb = vtb + bth;  // 192*1024 bf16

  pack_wt<<<96, 256, 0, stream>>>(Wq, Wk, Wv, wtb);
  qkv_mfma<<<(BB * TT) / 64, 256, 0, stream>>>(x, wtb, qb, kb, vtb);
  attn_mfma<<<512, 256, 0, stream>>>(qb, kb, vtb, out);
}

// Round 21
// 87.986 us; speedup vs baseline: 1.9500x; 1.9500x over previous
//
#include <hip/hip_runtime.h>
#include <hip/hip_bf16.h>
#include <math.h>

#define BB 16
#define TT 2048
#define DD 1024
#define HH 64
#define QK_SCALE 0.18033688011112042f  // 0.125 * log2(e)  (exp2-domain softmax)

typedef short bf16x8 __attribute__((ext_vector_type(8)));
typedef short bf16x4 __attribute__((ext_vector_type(4)));
typedef float f32x4 __attribute__((ext_vector_type(4)));

__device__ __forceinline__ short f2bf(float f) {  // RNE (cold paths only)
  union { float f; unsigned u; } c; c.f = f;
  unsigned u = c.u + 0x7FFFu + ((c.u >> 16) & 1u);
  return (short)(u >> 16);
}

// packed pair f32x2 -> bf16x2 (v_cvt_pk_bf16_f32 via standard cast API)
__device__ __forceinline__ unsigned pk2(float lo, float hi) {
  float2 t; t.x = lo; t.y = hi;
  __hip_bfloat162 h = __float22bfloat162_rn(t);
  union { __hip_bfloat162 h; unsigned u; } c; c.h = h;
  return c.u;
}

// Counted-vmcnt fences (T4)
#define FENCE_VM(N)                                        \
  do {                                                     \
    asm volatile("s_waitcnt vmcnt(" #N ")" ::: "memory");  \
    __builtin_amdgcn_sched_barrier(0);                     \
    __builtin_amdgcn_s_barrier();                          \
  } while (0)

// 64-col bf16 tile (128B row stride): XOR-swizzle 16B units by row&7.
__device__ __forceinline__ void* lds_swz(void* base, int row, int col) {
  int byte = (row << 7) + (col << 1);
  byte ^= (row & 7) << 4;
  return (void*)((char*)base + byte);
}

// ---------------------------------------------------------------------------
// Pack Wq|Wk|Wv (fp32 [D][H]) -> Wt bf16 [192][1024]
// ---------------------------------------------------------------------------
__global__ __launch_bounds__(256) void pack_wt(
    const float* __restrict__ Wq, const float* __restrict__ Wk,
    const float* __restrict__ Wv, short* __restrict__ wt) {
  const int idx = blockIdx.x * 256 + threadIdx.x;
  const int n = idx >> 7;
  const int k0 = (idx & 127) << 3;
  const float* W = (n < 64) ? Wq : (n < 128) ? Wk : Wv;
  const int h = n & 63;
  bf16x8 o;
#pragma unroll
  for (int j = 0; j < 8; ++j) o[j] = f2bf(W[(k0 + j) * HH + h]);
  *(bf16x8*)&wt[n * DD + k0] = o;
}

// ---------------------------------------------------------------------------
// QKV GEMM v10 = v9 with the fp32-tile swizzle widened &7 -> &15.
// fp32 rows are 256B = 2 bank-wraps; &7 only permuted within a half -> 8-way
// conflicts (R19: 6.3M). &15 spreads reads across all 16 units -> ~4-way.
// ---------------------------------------------------------------------------
__global__ __launch_bounds__(256, 2) void qkv_mfma(
    const float* __restrict__ x, const short* __restrict__ wt,
    short* __restrict__ qo, short* __restrict__ ko, short* __restrict__ vt) {
  __shared__ float xls[4][64 * 64];  // 4 x 16 KB fp32 tiles (64 KB)
  const int tid = threadIdx.x;
  const int lane = tid & 63;
  const int w = tid >> 6;
  const int q16 = lane & 15;
  const int g = lane >> 4;
  const size_t r0 = (size_t)blockIdx.x * 64;

  f32x4 acc[4][3];
#pragma unroll
  for (int mf = 0; mf < 4; ++mf)
#pragma unroll
    for (int nf = 0; nf < 3; ++nf) acc[mf][nf] = (f32x4){0.f, 0.f, 0.f, 0.f};

  const short* wp[3];
#pragma unroll
  for (int nf = 0; nf < 3; ++nf)
    wp[nf] = wt + (size_t)(w * 48 + nf * 16 + q16) * DD + g * 8;

  const int srow_b = w * 16 + (lane >> 4);  // row for j=0; j adds 4
  const int ul = lane & 15;                 // linear 16B-unit within row

  bf16x8 bcur[3][2];
#pragma unroll
  for (int nf = 0; nf < 3; ++nf)
#pragma unroll
    for (int kf = 0; kf < 2; ++kf)
      bcur[nf][kf] = *(const bf16x8*)(wp[nf] + kf * 32);
#pragma unroll
  for (int t = 0; t < 3; ++t)
#pragma unroll
    for (int j = 0; j < 4; ++j) {
      const int row = srow_b + j * 4;
      const int us = ul ^ (row & 15);
      const float* src = x + (r0 + row) * DD + t * 64 + us * 4;
      __builtin_amdgcn_global_load_lds(
          (const __attribute__((address_space(1))) void*)src,
          (__attribute__((address_space(3))) void*)(&xls[t][0] + (w * 4 + j) * 256),
          16, 0, 0);
    }
  __builtin_amdgcn_sched_barrier(0);
  FENCE_VM(8);

  for (int ks = 0; ks < 16; ++ks) {
    const float* bufc = &xls[ks & 3][0];

    bf16x8 bnxt[3][2];
    if (ks < 15) {
      const int k1 = (ks + 1) << 6;
#pragma unroll
      for (int nf = 0; nf < 3; ++nf)
#pragma unroll
        for (int kf = 0; kf < 2; ++kf)
          bnxt[nf][kf] = *(const bf16x8*)(wp[nf] + k1 + kf * 32);
    }
    if (ks <= 12) {
#pragma unroll
      for (int j = 0; j < 4; ++j) {
        const int row = srow_b + j * 4;
        const int us = ul ^ (row & 15);
        const float* src = x + (r0 + row) * DD + (ks + 3) * 64 + us * 4;
        __builtin_amdgcn_global_load_lds(
            (const __attribute__((address_space(1))) void*)src,
            (__attribute__((address_space(3))) void*)(&xls[(ks + 3) & 3][0] +
                                                      (w * 4 + j) * 256),
            16, 0, 0);
      }
    }
    __builtin_amdgcn_sched_barrier(0);

    bf16x8 afr[4][2];
#pragma unroll
    for (int mf = 0; mf < 4; ++mf)
#pragma unroll
      for (int kf = 0; kf < 2; ++kf) {
        const int R = mf * 16 + q16;
        const int r15 = R & 15;
        const int u0 = kf * 8 + g * 2;
        const float4 fa = *(const float4*)(bufc + R * 64 + ((u0 ^ r15) << 2));
        const float4 fb = *(const float4*)(bufc + R * 64 + (((u0 + 1) ^ r15) << 2));
        unsigned* up = (unsigned*)&afr[mf][kf];
        up[0] = pk2(fa.x, fa.y);
        up[1] = pk2(fa.z, fa.w);
        up[2] = pk2(fb.x, fb.y);
        up[3] = pk2(fb.z, fb.w);
      }

#pragma unroll
    for (int mf = 0; mf < 4; ++mf)
#pragma unroll
      for (int nf = 0; nf < 3; ++nf)
#pragma unroll
        for (int kf = 0; kf < 2; ++kf)
          acc[mf][nf] = __builtin_amdgcn_mfma_f32_16x16x32_bf16(
              afr[mf][kf], bcur[nf][kf], acc[mf][nf], 0, 0, 0);

    if (ks < 15) {
      if (ks <= 12) FENCE_VM(14);
      else if (ks == 13) FENCE_VM(10);
      else FENCE_VM(6);
#pragma unroll
      for (int nf = 0; nf < 3; ++nf)
#pragma unroll
        for (int kf = 0; kf < 2; ++kf) bcur[nf][kf] = bnxt[nf][kf];
    }
  }

#pragma unroll
  for (int nf = 0; nf < 3; ++nf) {
    const int n = w * 48 + nf * 16 + q16;
    const int mat = n >> 6;
    const int h = n & 63;
    if (mat < 2) {
      short* outp = mat ? ko : qo;
      const float fac = mat ? 1.0f : QK_SCALE;
#pragma unroll
      for (int mf = 0; mf < 4; ++mf)
#pragma unroll
        for (int r = 0; r < 4; ++r)
          outp[(r0 + mf * 16 + g * 4 + r) * HH + h] = f2bf(acc[mf][nf][r] * fac);
    } else {
      const int bb = (int)(r0 >> 11);
      const int tloc = (int)(r0 & 2047);
#pragma unroll
      for (int mf = 0; mf < 4; ++mf) {
        uint2 pkv;
        pkv.x = pk2(acc[mf][nf][0], acc[mf][nf][1]);
        pkv.y = pk2(acc[mf][nf][2], acc[mf][nf][3]);
        *(uint2*)&vt[((size_t)bb * HH + h) * TT + tloc + mf * 16 + g * 4] = pkv;
      }
    }
  }
}

// ---------------------------------------------------------------------------
// Flash attention v10: K/V staged via global_load_lds (pre-swizzled per-lane
// source, linear dest, 4 DMA ops/wave/chunk), issued a full chunk early with
// one counted fence per chunk. Removes the reg-roundtrip (12 loads + 8
// ds_writes + shuffles of VALU per chunk). PV = round-8 verified pattern:
// linear V^T tile, two ds_read_b64 per B-frag (2-way banks = free).
// ---------------------------------------------------------------------------
__global__ __launch_bounds__(256, 4) void attn_mfma(
    const short* __restrict__ q, const short* __restrict__ k,
    const short* __restrict__ vt, float* __restrict__ out) {
  __shared__ short klds[2][64 * 64];  // 8 KB, K [key][d], swizzled via source
  __shared__ short vlds[2][64 * 64];  // 8 KB, V^T [h][key], swizzled via source

  const int id = blockIdx.x;  // 0..511
  const int b = (id & 7) | (((id >> 3) & 1) << 3);
  const int kk = id >> 4;
  const int qt = (kk < 16) ? (31 - kk) : (kk - 16);
  const int t0 = qt << 6;
  const int tid = threadIdx.x;
  const int lane = tid & 63;
  const int w = tid >> 6;
  const int q16 = lane & 15;
  const int g = lane >> 4;
  const int NC = qt + 1;

  const size_t brow = (size_t)b * TT;
  const short* kg = k + brow * HH;
  const short* vtg = vt + (size_t)b * HH * TT;

  // DMA staging geometry: per call a wave covers 8 rows (8 lanes' 16B each
  // per row); us encodes the read-side swizzle (logical unit ul^(row&7)).
  const int drow = lane >> 3;             // 0..7 within call
  const int us8 = (lane & 7) ^ drow;      // (ul ^ (row&7)), w/j-independent
  // per-call row base: w*16 + 8*j ; LDS dest: base + (w*16+8*j)*64 shorts

  // ---- stage Q into klds[0] (reg path), pull per-wave Q frags ----
  {
    const int srow = tid >> 2;
    const int scol = (tid & 3) << 4;
    const short* qsrc = q + (brow + t0 + srow) * HH;
    *(bf16x8*)lds_swz(klds[0], srow, scol) = *(const bf16x8*)&qsrc[scol];
    *(bf16x8*)lds_swz(klds[0], srow, scol + 8) = *(const bf16x8*)&qsrc[scol + 8];
  }
  __syncthreads();
  bf16x8 qa[2];
#pragma unroll
  for (int kf = 0; kf < 2; ++kf)
    qa[kf] = *(bf16x8*)lds_swz(klds[0], w * 16 + q16, kf * 32 + g * 8);
  __syncthreads();  // all waves done reading Q before DMA overwrites klds[0]

  // ---- issue chunk-0 K/V DMA ----
#pragma unroll
  for (int j = 0; j < 2; ++j) {
    const int row = w * 16 + 8 * j + drow;
    __builtin_amdgcn_global_load_lds(
        (const __attribute__((address_space(1))) void*)(kg + row * HH + 8 * us8),
        (__attribute__((address_space(3))) void*)(&klds[0][(w * 16 + 8 * j) * 64]),
        16, 0, 0);
    __builtin_amdgcn_global_load_lds(
        (const __attribute__((address_space(1))) void*)(vtg + row * TT + 8 * us8),
        (__attribute__((address_space(3))) void*)(&vlds[0][(w * 16 + 8 * j) * 64]),
        16, 0, 0);
  }
  __builtin_amdgcn_sched_barrier(0);
  FENCE_VM(0);

  f32x4 po[4];
  f32x4 lacc = (f32x4){0.f, 0.f, 0.f, 0.f};
  float m = -INFINITY;
#pragma unroll
  for (int nf = 0; nf < 4; ++nf) po[nf] = (f32x4){0.f, 0.f, 0.f, 0.f};

  const bf16x8 ones = {0x3F80, 0x3F80, 0x3F80, 0x3F80,
                       0x3F80, 0x3F80, 0x3F80, 0x3F80};
  int cur = 0;

  for (int c = 0; c < NC; ++c) {
    const bool notlast = (c + 1 < NC);
    if (notlast) {  // issue next chunk's DMA into the other buffer
      const int s1 = (c + 1) << 6;
#pragma unroll
      for (int j = 0; j < 2; ++j) {
        const int row = w * 16 + 8 * j + drow;
        __builtin_amdgcn_global_load_lds(
            (const __attribute__((address_space(1))) void*)(kg + (s1 + row) * HH + 8 * us8),
            (__attribute__((address_space(3))) void*)(&klds[cur ^ 1][(w * 16 + 8 * j) * 64]),
            16, 0, 0);
        __builtin_amdgcn_global_load_lds(
            (const __attribute__((address_space(1))) void*)(vtg + row * TT + s1 + 8 * us8),
            (__attribute__((address_space(3))) void*)(&vlds[cur ^ 1][(w * 16 + 8 * j) * 64]),
            16, 0, 0);
      }
      __builtin_amdgcn_sched_barrier(0);
    }

    // ---- S^T = K . Q^T ----
    f32x4 sfr[4];
#pragma unroll
    for (int nf = 0; nf < 4; ++nf) sfr[nf] = (f32x4){0.f, 0.f, 0.f, 0.f};
    __builtin_amdgcn_s_setprio(1);
#pragma unroll
    for (int nf = 0; nf < 4; ++nf)
#pragma unroll
      for (int kf = 0; kf < 2; ++kf) {
        bf16x8 kb = *(bf16x8*)lds_swz(klds[cur], nf * 16 + q16, kf * 32 + g * 8);
        sfr[nf] = __builtin_amdgcn_mfma_f32_16x16x32_bf16(kb, qa[kf], sfr[nf], 0, 0, 0);
      }
    __builtin_amdgcn_s_setprio(0);

    // ---- causal mask (diagonal chunk only) ----
    if (c == NC - 1) {
      const int qloc = w * 16 + q16;
#pragma unroll
      for (int nf = 0; nf < 4; ++nf)
#pragma unroll
        for (int r = 0; r < 4; ++r)
          if (16 * nf + 4 * g + r > qloc) sfr[nf][r] = -INFINITY;
    }

    // ---- row max: per-lane 16 keys, then across g-groups ----
    float pm;
    {
      f32x4 t01 = (f32x4){fmaxf(sfr[0][0], sfr[1][0]), fmaxf(sfr[0][1], sfr[1][1]),
                          fmaxf(sfr[0][2], sfr[1][2]), fmaxf(sfr[0][3], sfr[1][3])};
      f32x4 t23 = (f32x4){fmaxf(sfr[2][0], sfr[3][0]), fmaxf(sfr[2][1], sfr[3][1]),
                          fmaxf(sfr[2][2], sfr[3][2]), fmaxf(sfr[2][3], sfr[3][3])};
      pm = fmaxf(fmaxf(fmaxf(t01[0], t23[0]), fmaxf(t01[1], t23[1])),
                 fmaxf(fmaxf(t01[2], t23[2]), fmaxf(t01[3], t23[3])));
      pm = fmaxf(pm, __shfl_xor(pm, 16));
      pm = fmaxf(pm, __shfl_xor(pm, 32));
    }

    // ---- defer-max (T13) ----
    if (__any(pm - m > 8.f)) {
      const float mn = fmaxf(m, pm);
      const float corr = exp2f(m - mn);
      m = mn;
      const int sbase = (lane & 48) + ((lane >> 4) << 2);
#pragma unroll
      for (int r = 0; r < 4; ++r) {
        const float cr = __shfl(corr, sbase + r);
        lacc[r] *= cr;
#pragma unroll
        for (int nf = 0; nf < 4; ++nf) po[nf][r] *= cr;
      }
    }

    // ---- P = exp2(S - m) -> bf16 A-frags (key map 32m2+16(j>>2)+4g+(j&3)) ----
    bf16x8 pa[2];
#pragma unroll
    for (int m2 = 0; m2 < 2; ++m2) {
      float e0 = exp2f(sfr[2 * m2][0] - m), e1 = exp2f(sfr[2 * m2][1] - m);
      float e2 = exp2f(sfr[2 * m2][2] - m), e3 = exp2f(sfr[2 * m2][3] - m);
      float e4 = exp2f(sfr[2 * m2 + 1][0] - m), e5 = exp2f(sfr[2 * m2 + 1][1] - m);
      float e6 = exp2f(sfr[2 * m2 + 1][2] - m), e7 = exp2f(sfr[2 * m2 + 1][3] - m);
      unsigned* up = (unsigned*)&pa[m2];
      up[0] = pk2(e0, e1); up[1] = pk2(e2, e3);
      up[2] = pk2(e4, e5); up[3] = pk2(e6, e7);
    }

    // ---- O += P.V ; l += P.1  (two b64 reads per B-frag, round-8 map) ----
    __builtin_amdgcn_s_setprio(1);
#pragma unroll
    for (int m2 = 0; m2 < 2; ++m2) {
#pragma unroll
      for (int nf = 0; nf < 4; ++nf) {
        bf16x4 lo = *(bf16x4*)lds_swz(vlds[cur], nf * 16 + q16, 32 * m2 + 4 * g);
        bf16x4 hi = *(bf16x4*)lds_swz(vlds[cur], nf * 16 + q16, 32 * m2 + 16 + 4 * g);
        bf16x8 vb = __builtin_shufflevector(lo, hi, 0, 1, 2, 3, 4, 5, 6, 7);
        po[nf] = __builtin_amdgcn_mfma_f32_16x16x32_bf16(pa[m2], vb, po[nf], 0, 0, 0);
      }
      lacc = __builtin_amdgcn_mfma_f32_16x16x32_bf16(pa[m2], ones, lacc, 0, 0, 0);
    }
    __builtin_amdgcn_s_setprio(0);

    if (notlast) {
      FENCE_VM(0);  // chunk c+1 staged; all waves past reads of cur
      cur ^= 1;
    }
  }

  const int qrow = t0 + w * 16 + g * 4;
#pragma unroll
  for (int nf = 0; nf < 4; ++nf) {
    const int h = nf * 16 + q16;
#pragma unroll
    for (int r = 0; r < 4; ++r)
      out[(brow + qrow + r) * HH + h] = po[nf][r] / lacc[r];
  }
}

extern "C" void kernel_launch(void* const* d_in, const int* in_sizes, int n_in,
                              void* d_out, int out_size, void* d_ws, size_t ws_size,
                              hipStream_t stream) {
  const float* x  = (const float*)d_in[0];
  const float* Wq = (const float*)d_in[1];
  const float* Wk = (const float*)d_in[2];
  const float* Wv = (const float*)d_in[3];
  float* out = (float*)d_out;

  const size_t bth = (size_t)BB * TT * HH;  // 2,097,152
  short* qb  = (short*)d_ws;
  short* kb  = qb + bth;
  short* vtb = kb + bth;
  short* wtb = vtb + bth;  // 192*1024 bf16

  pack_wt<<<96, 256, 0, stream>>>(Wq, Wk, Wv, wtb);
  qkv_mfma<<<(BB * TT) / 64, 256, 0, stream>>>(x, wtb, qb, kb, vtb);
  attn_mfma<<<512, 256, 0, stream>>>(qb, kb, vtb, out);
}

// Round 22
// 78.549 us; speedup vs baseline: 2.1842x; 1.1201x over previous
//
#include <hip/hip_runtime.h>
#include <hip/hip_bf16.h>
#include <math.h>

#define BB 16
#define TT 2048
#define DD 1024
#define HH 64
#define QK_SCALE 0.18033688011112042f  // 0.125 * log2(e)  (exp2-domain softmax)

typedef short bf16x8 __attribute__((ext_vector_type(8)));
typedef short bf16x4 __attribute__((ext_vector_type(4)));
typedef float f32x4 __attribute__((ext_vector_type(4)));

__device__ __forceinline__ short f2bf(float f) {  // RNE (cold paths only)
  union { float f; unsigned u; } c; c.f = f;
  unsigned u = c.u + 0x7FFFu + ((c.u >> 16) & 1u);
  return (short)(u >> 16);
}

// packed pair f32x2 -> bf16x2 (v_cvt_pk_bf16_f32 via standard cast API)
__device__ __forceinline__ unsigned pk2(float lo, float hi) {
  float2 t; t.x = lo; t.y = hi;
  __hip_bfloat162 h = __float22bfloat162_rn(t);
  union { __hip_bfloat162 h; unsigned u; } c; c.h = h;
  return c.u;
}

// Counted-vmcnt fences (T4)
#define FENCE_VM(N)                                        \
  do {                                                     \
    asm volatile("s_waitcnt vmcnt(" #N ")" ::: "memory");  \
    __builtin_amdgcn_sched_barrier(0);                     \
    __builtin_amdgcn_s_barrier();                          \
  } while (0)

// 64-col bf16 tile (128B row stride): XOR-swizzle 16B units by row&7.
__device__ __forceinline__ void* lds_swz(void* base, int row, int col) {
  int byte = (row << 7) + (col << 1);
  byte ^= (row & 7) << 4;
  return (void*)((char*)base + byte);
}

// ---------------------------------------------------------------------------
// Pack Wq|Wk|Wv (fp32 [D][H]) -> Wt bf16 [192][1024]
// ---------------------------------------------------------------------------
__global__ __launch_bounds__(256) void pack_wt(
    const float* __restrict__ Wq, const float* __restrict__ Wk,
    const float* __restrict__ Wv, short* __restrict__ wt) {
  const int idx = blockIdx.x * 256 + threadIdx.x;
  const int n = idx >> 7;
  const int k0 = (idx & 127) << 3;
  const float* W = (n < 64) ? Wq : (n < 128) ? Wk : Wv;
  const int h = n & 63;
  bf16x8 o;
#pragma unroll
  for (int j = 0; j < 8; ++j) o[j] = f2bf(W[(k0 + j) * HH + h]);
  *(bf16x8*)&wt[n * DD + k0] = o;
}

// ---------------------------------------------------------------------------
// QKV GEMM = round-18 v9 with ONLY the fp32-tile swizzle widened &7 -> &15
// (fp32 rows are 256B = 2 bank-wraps; &7 permuted within a half -> 8-way
// conflicts, 6.3M measured in R19; &15 spreads across all 16 units).
// ---------------------------------------------------------------------------
__global__ __launch_bounds__(256, 2) void qkv_mfma(
    const float* __restrict__ x, const short* __restrict__ wt,
    short* __restrict__ qo, short* __restrict__ ko, short* __restrict__ vt) {
  __shared__ float xls[4][64 * 64];  // 4 x 16 KB fp32 tiles (64 KB)
  const int tid = threadIdx.x;
  const int lane = tid & 63;
  const int w = tid >> 6;
  const int q16 = lane & 15;
  const int g = lane >> 4;
  const size_t r0 = (size_t)blockIdx.x * 64;

  f32x4 acc[4][3];
#pragma unroll
  for (int mf = 0; mf < 4; ++mf)
#pragma unroll
    for (int nf = 0; nf < 3; ++nf) acc[mf][nf] = (f32x4){0.f, 0.f, 0.f, 0.f};

  const short* wp[3];
#pragma unroll
  for (int nf = 0; nf < 3; ++nf)
    wp[nf] = wt + (size_t)(w * 48 + nf * 16 + q16) * DD + g * 8;

  const int srow_b = w * 16 + (lane >> 4);  // row for j=0; j adds 4
  const int ul = lane & 15;                 // linear 16B-unit within row

  bf16x8 bcur[3][2];
#pragma unroll
  for (int nf = 0; nf < 3; ++nf)
#pragma unroll
    for (int kf = 0; kf < 2; ++kf)
      bcur[nf][kf] = *(const bf16x8*)(wp[nf] + kf * 32);
#pragma unroll
  for (int t = 0; t < 3; ++t)
#pragma unroll
    for (int j = 0; j < 4; ++j) {
      const int row = srow_b + j * 4;
      const int us = ul ^ (row & 15);
      const float* src = x + (r0 + row) * DD + t * 64 + us * 4;
      __builtin_amdgcn_global_load_lds(
          (const __attribute__((address_space(1))) void*)src,
          (__attribute__((address_space(3))) void*)(&xls[t][0] + (w * 4 + j) * 256),
          16, 0, 0);
    }
  __builtin_amdgcn_sched_barrier(0);
  FENCE_VM(8);

  for (int ks = 0; ks < 16; ++ks) {
    const float* bufc = &xls[ks & 3][0];

    bf16x8 bnxt[3][2];
    if (ks < 15) {
      const int k1 = (ks + 1) << 6;
#pragma unroll
      for (int nf = 0; nf < 3; ++nf)
#pragma unroll
        for (int kf = 0; kf < 2; ++kf)
          bnxt[nf][kf] = *(const bf16x8*)(wp[nf] + k1 + kf * 32);
    }
    if (ks <= 12) {
#pragma unroll
      for (int j = 0; j < 4; ++j) {
        const int row = srow_b + j * 4;
        const int us = ul ^ (row & 15);
        const float* src = x + (r0 + row) * DD + (ks + 3) * 64 + us * 4;
        __builtin_amdgcn_global_load_lds(
            (const __attribute__((address_space(1))) void*)src,
            (__attribute__((address_space(3))) void*)(&xls[(ks + 3) & 3][0] +
                                                      (w * 4 + j) * 256),
            16, 0, 0);
      }
    }
    __builtin_amdgcn_sched_barrier(0);

    bf16x8 afr[4][2];
#pragma unroll
    for (int mf = 0; mf < 4; ++mf)
#pragma unroll
      for (int kf = 0; kf < 2; ++kf) {
        const int R = mf * 16 + q16;
        const int r15 = R & 15;
        const int u0 = kf * 8 + g * 2;
        const float4 fa = *(const float4*)(bufc + R * 64 + ((u0 ^ r15) << 2));
        const float4 fb = *(const float4*)(bufc + R * 64 + (((u0 + 1) ^ r15) << 2));
        unsigned* up = (unsigned*)&afr[mf][kf];
        up[0] = pk2(fa.x, fa.y);
        up[1] = pk2(fa.z, fa.w);
        up[2] = pk2(fb.x, fb.y);
        up[3] = pk2(fb.z, fb.w);
      }

#pragma unroll
    for (int mf = 0; mf < 4; ++mf)
#pragma unroll
      for (int nf = 0; nf < 3; ++nf)
#pragma unroll
        for (int kf = 0; kf < 2; ++kf)
          acc[mf][nf] = __builtin_amdgcn_mfma_f32_16x16x32_bf16(
              afr[mf][kf], bcur[nf][kf], acc[mf][nf], 0, 0, 0);

    if (ks < 15) {
      if (ks <= 12) FENCE_VM(14);
      else if (ks == 13) FENCE_VM(10);
      else FENCE_VM(6);
#pragma unroll
      for (int nf = 0; nf < 3; ++nf)
#pragma unroll
        for (int kf = 0; kf < 2; ++kf) bcur[nf][kf] = bnxt[nf][kf];
    }
  }

#pragma unroll
  for (int nf = 0; nf < 3; ++nf) {
    const int n = w * 48 + nf * 16 + q16;
    const int mat = n >> 6;
    const int h = n & 63;
    if (mat < 2) {
      short* outp = mat ? ko : qo;
      const float fac = mat ? 1.0f : QK_SCALE;
#pragma unroll
      for (int mf = 0; mf < 4; ++mf)
#pragma unroll
        for (int r = 0; r < 4; ++r)
          outp[(r0 + mf * 16 + g * 4 + r) * HH + h] = f2bf(acc[mf][nf][r] * fac);
    } else {
      const int bb = (int)(r0 >> 11);
      const int tloc = (int)(r0 & 2047);
#pragma unroll
      for (int mf = 0; mf < 4; ++mf) {
        uint2 pkv;
        pkv.x = pk2(acc[mf][nf][0], acc[mf][nf][1]);
        pkv.y = pk2(acc[mf][nf][2], acc[mf][nf][3]);
        *(uint2*)&vt[((size_t)bb * HH + h) * TT + tloc + mf * 16 + g * 4] = pkv;
      }
    }
  }
}

// ---------------------------------------------------------------------------
// Flash attention (round-10/18 structure — best measured; reg-staged K/V).
// ---------------------------------------------------------------------------
__global__ __launch_bounds__(256, 4) void attn_mfma(
    const short* __restrict__ q, const short* __restrict__ k,
    const short* __restrict__ vt, float* __restrict__ out) {
  __shared__ short klds[2][64 * 64];
  __shared__ short vlds[2][64 * 64];

  const int id = blockIdx.x;  // 0..511
  const int b = (id & 7) | (((id >> 3) & 1) << 3);
  const int kk = id >> 4;
  const int qt = (kk < 16) ? (31 - kk) : (kk - 16);
  const int t0 = qt << 6;
  const int tid = threadIdx.x;
  const int lane = tid & 63;
  const int w = tid >> 6;
  const int q16 = lane & 15;
  const int g = lane >> 4;
  const int NC = qt + 1;

  const size_t brow = (size_t)b * TT;
  const short* kg = k + brow * HH;
  const short* vtg = vt + (size_t)b * HH * TT;

  const int srow = tid >> 2;
  const int scol = (tid & 3) << 4;

  const int vgA = (scol >> 3) & 3;
  const int vgB = ((scol + 8) >> 3) & 3;
  const int vm2 = scol >> 5;
  const short* vrow_p = vtg + srow * TT + vm2 * 32;

  bf16x8 kr0 = *(const bf16x8*)&kg[srow * HH + scol];
  bf16x8 kr1 = *(const bf16x8*)&kg[srow * HH + scol + 8];
  bf16x4 va0 = *(const bf16x4*)(vrow_p + 4 * vgA);
  bf16x4 va1 = *(const bf16x4*)(vrow_p + 16 + 4 * vgA);
  bf16x4 vb0 = *(const bf16x4*)(vrow_p + 4 * vgB);
  bf16x4 vb1 = *(const bf16x4*)(vrow_p + 16 + 4 * vgB);

  {
    const short* qsrc = q + (brow + t0 + srow) * HH;
    *(bf16x8*)lds_swz(klds[0], srow, scol) = *(const bf16x8*)&qsrc[scol];
    *(bf16x8*)lds_swz(klds[0], srow, scol + 8) = *(const bf16x8*)&qsrc[scol + 8];
  }
  __syncthreads();
  bf16x8 qa[2];
#pragma unroll
  for (int kf = 0; kf < 2; ++kf)
    qa[kf] = *(bf16x8*)lds_swz(klds[0], w * 16 + q16, kf * 32 + g * 8);
  __syncthreads();

  *(bf16x8*)lds_swz(klds[0], srow, scol) = kr0;
  *(bf16x8*)lds_swz(klds[0], srow, scol + 8) = kr1;
  *(bf16x8*)lds_swz(vlds[0], srow, scol) =
      __builtin_shufflevector(va0, va1, 0, 1, 2, 3, 4, 5, 6, 7);
  *(bf16x8*)lds_swz(vlds[0], srow, scol + 8) =
      __builtin_shufflevector(vb0, vb1, 0, 1, 2, 3, 4, 5, 6, 7);
  __syncthreads();

  f32x4 po[4];
  f32x4 lacc = (f32x4){0.f, 0.f, 0.f, 0.f};
  float m = -INFINITY;
#pragma unroll
  for (int nf = 0; nf < 4; ++nf) po[nf] = (f32x4){0.f, 0.f, 0.f, 0.f};

  const bf16x8 ones = {0x3F80, 0x3F80, 0x3F80, 0x3F80,
                       0x3F80, 0x3F80, 0x3F80, 0x3F80};
  int cur = 0;

  for (int c = 0; c < NC; ++c) {
    const bool notlast = (c + 1 < NC);
    if (notlast) {
      const int s1 = (c + 1) << 6;
      kr0 = *(const bf16x8*)&kg[(s1 + srow) * HH + scol];
      kr1 = *(const bf16x8*)&kg[(s1 + srow) * HH + scol + 8];
      va0 = *(const bf16x4*)(vrow_p + s1 + 4 * vgA);
      va1 = *(const bf16x4*)(vrow_p + s1 + 16 + 4 * vgA);
      vb0 = *(const bf16x4*)(vrow_p + s1 + 4 * vgB);
      vb1 = *(const bf16x4*)(vrow_p + s1 + 16 + 4 * vgB);
    }

    f32x4 sfr[4];
#pragma unroll
    for (int nf = 0; nf < 4; ++nf) sfr[nf] = (f32x4){0.f, 0.f, 0.f, 0.f};
    __builtin_amdgcn_s_setprio(1);
#pragma unroll
    for (int nf = 0; nf < 4; ++nf)
#pragma unroll
      for (int kf = 0; kf < 2; ++kf) {
        bf16x8 kb = *(bf16x8*)lds_swz(klds[cur], nf * 16 + q16, kf * 32 + g * 8);
        sfr[nf] = __builtin_amdgcn_mfma_f32_16x16x32_bf16(kb, qa[kf], sfr[nf], 0, 0, 0);
      }
    __builtin_amdgcn_s_setprio(0);

    if (c == NC - 1) {
      const int qloc = w * 16 + q16;
#pragma unroll
      for (int nf = 0; nf < 4; ++nf)
#pragma unroll
        for (int r = 0; r < 4; ++r)
          if (16 * nf + 4 * g + r > qloc) sfr[nf][r] = -INFINITY;
    }

    float pm;
    {
      f32x4 t01 = (f32x4){fmaxf(sfr[0][0], sfr[1][0]), fmaxf(sfr[0][1], sfr[1][1]),
                          fmaxf(sfr[0][2], sfr[1][2]), fmaxf(sfr[0][3], sfr[1][3])};
      f32x4 t23 = (f32x4){fmaxf(sfr[2][0], sfr[3][0]), fmaxf(sfr[2][1], sfr[3][1]),
                          fmaxf(sfr[2][2], sfr[3][2]), fmaxf(sfr[2][3], sfr[3][3])};
      pm = fmaxf(fmaxf(fmaxf(t01[0], t23[0]), fmaxf(t01[1], t23[1])),
                 fmaxf(fmaxf(t01[2], t23[2]), fmaxf(t01[3], t23[3])));
      pm = fmaxf(pm, __shfl_xor(pm, 16));
      pm = fmaxf(pm, __shfl_xor(pm, 32));
    }

    if (__any(pm - m > 8.f)) {
      const float mn = fmaxf(m, pm);
      const float corr = exp2f(m - mn);
      m = mn;
      const int sbase = (lane & 48) + ((lane >> 4) << 2);
#pragma unroll
      for (int r = 0; r < 4; ++r) {
        const float cr = __shfl(corr, sbase + r);
        lacc[r] *= cr;
#pragma unroll
        for (int nf = 0; nf < 4; ++nf) po[nf][r] *= cr;
      }
    }

    bf16x8 pa[2];
#pragma unroll
    for (int m2 = 0; m2 < 2; ++m2) {
      float e0 = exp2f(sfr[2 * m2][0] - m), e1 = exp2f(sfr[2 * m2][1] - m);
      float e2 = exp2f(sfr[2 * m2][2] - m), e3 = exp2f(sfr[2 * m2][3] - m);
      float e4 = exp2f(sfr[2 * m2 + 1][0] - m), e5 = exp2f(sfr[2 * m2 + 1][1] - m);
      float e6 = exp2f(sfr[2 * m2 + 1][2] - m), e7 = exp2f(sfr[2 * m2 + 1][3] - m);
      unsigned* up = (unsigned*)&pa[m2];
      up[0] = pk2(e0, e1); up[1] = pk2(e2, e3);
      up[2] = pk2(e4, e5); up[3] = pk2(e6, e7);
    }

    __builtin_amdgcn_s_setprio(1);
#pragma unroll
    for (int m2 = 0; m2 < 2; ++m2) {
#pragma unroll
      for (int nf = 0; nf < 4; ++nf) {
        bf16x8 vb = *(bf16x8*)lds_swz(vlds[cur], nf * 16 + q16, m2 * 32 + g * 8);
        po[nf] = __builtin_amdgcn_mfma_f32_16x16x32_bf16(pa[m2], vb, po[nf], 0, 0, 0);
      }
      lacc = __builtin_amdgcn_mfma_f32_16x16x32_bf16(pa[m2], ones, lacc, 0, 0, 0);
    }
    __builtin_amdgcn_s_setprio(0);

    if (notlast) {
      *(bf16x8*)lds_swz(klds[cur ^ 1], srow, scol) = kr0;
      *(bf16x8*)lds_swz(klds[cur ^ 1], srow, scol + 8) = kr1;
      *(bf16x8*)lds_swz(vlds[cur ^ 1], srow, scol) =
          __builtin_shufflevector(va0, va1, 0, 1, 2, 3, 4, 5, 6, 7);
      *(bf16x8*)lds_swz(vlds[cur ^ 1], srow, scol + 8) =
          __builtin_shufflevector(vb0, vb1, 0, 1, 2, 3, 4, 5, 6, 7);
      __syncthreads();
      cur ^= 1;
    }
  }

  const int qrow = t0 + w * 16 + g * 4;
#pragma unroll
  for (int nf = 0; nf < 4; ++nf) {
    const int h = nf * 16 + q16;
#pragma unroll
    for (int r = 0; r < 4; ++r)
      out[(brow + qrow + r) * HH + h] = po[nf][r] / lacc[r];
  }
}

extern "C" void kernel_launch(void* const* d_in, const int* in_sizes, int n_in,
                              void* d_out, int out_size, void* d_ws, size_t ws_size,
                              hipStream_t stream) {
  const float* x  = (const float*)d_in[0];
  const float* Wq = (const float*)d_in[1];
  const float* Wk = (const float*)d_in[2];
  const float* Wv = (const float*)d_in[3];
  float* out = (float*)d_out;

  const size_t bth = (size_t)BB * TT * HH;  // 2,097,152
  short* qb  = (short*)d_ws;
  short* kb  = qb + bth;
  short* vtb = kb + bth;
  short* wtb = vtb + bth;  // 192*1024 bf16

  pack_wt<<<96, 256, 0, stream>>>(Wq, Wk, Wv, wtb);
  qkv_mfma<<<(BB * TT) / 64, 256, 0, stream>>>(x, wtb, qb, kb, vtb);
  attn_mfma<<<512, 256, 0, stream>>>(qb, kb, vtb, out);
}

// Round 23
// 78.328 us; speedup vs baseline: 2.1904x; 1.0028x over previous
//
#include <hip/hip_runtime.h>
#include <hip/hip_bf16.h>
#include <math.h>

#define BB 16
#define TT 2048
#define DD 1024
#define HH 64
#define QK_SCALE 0.18033688011112042f  // 0.125 * log2(e)  (exp2-domain softmax)

typedef short bf16x8 __attribute__((ext_vector_type(8)));
typedef short bf16x4 __attribute__((ext_vector_type(4)));
typedef float f32x4 __attribute__((ext_vector_type(4)));

__device__ __forceinline__ short f2bf(float f) {  // RNE (cold paths only)
  union { float f; unsigned u; } c; c.f = f;
  unsigned u = c.u + 0x7FFFu + ((c.u >> 16) & 1u);
  return (short)(u >> 16);
}

// packed pair f32x2 -> bf16x2 (v_cvt_pk_bf16_f32 via standard cast API)
__device__ __forceinline__ unsigned pk2(float lo, float hi) {
  float2 t; t.x = lo; t.y = hi;
  __hip_bfloat162 h = __float22bfloat162_rn(t);
  union { __hip_bfloat162 h; unsigned u; } c; c.h = h;
  return c.u;
}

// Counted-vmcnt fences (T4)
#define FENCE_VM(N)                                        \
  do {                                                     \
    asm volatile("s_waitcnt vmcnt(" #N ")" ::: "memory");  \
    __builtin_amdgcn_sched_barrier(0);                     \
    __builtin_amdgcn_s_barrier();                          \
  } while (0)

// 64-col bf16 tile (128B row stride): XOR-swizzle 16B units by row&7.
__device__ __forceinline__ void* lds_swz(void* base, int row, int col) {
  int byte = (row << 7) + (col << 1);
  byte ^= (row & 7) << 4;
  return (void*)((char*)base + byte);
}

// ---------------------------------------------------------------------------
// Pack Wq|Wk|Wv (fp32 [D][H]) -> Wt bf16 [192][1024]
// ---------------------------------------------------------------------------
__global__ __launch_bounds__(256) void pack_wt(
    const float* __restrict__ Wq, const float* __restrict__ Wk,
    const float* __restrict__ Wv, short* __restrict__ wt) {
  const int idx = blockIdx.x * 256 + threadIdx.x;
  const int n = idx >> 7;
  const int k0 = (idx & 127) << 3;
  const float* W = (n < 64) ? Wq : (n < 128) ? Wk : Wv;
  const int h = n & 63;
  bf16x8 o;
#pragma unroll
  for (int j = 0; j < 8; ++j) o[j] = f2bf(W[(k0 + j) * HH + h]);
  *(bf16x8*)&wt[n * DD + k0] = o;
}

// ---------------------------------------------------------------------------
// QKV GEMM (round-22 best: global_load_lds fp32 staging, depth-3, &15 swz).
// ---------------------------------------------------------------------------
__global__ __launch_bounds__(256, 2) void qkv_mfma(
    const float* __restrict__ x, const short* __restrict__ wt,
    short* __restrict__ qo, short* __restrict__ ko, short* __restrict__ vt) {
  __shared__ float xls[4][64 * 64];  // 4 x 16 KB fp32 tiles (64 KB)
  const int tid = threadIdx.x;
  const int lane = tid & 63;
  const int w = tid >> 6;
  const int q16 = lane & 15;
  const int g = lane >> 4;
  const size_t r0 = (size_t)blockIdx.x * 64;

  f32x4 acc[4][3];
#pragma unroll
  for (int mf = 0; mf < 4; ++mf)
#pragma unroll
    for (int nf = 0; nf < 3; ++nf) acc[mf][nf] = (f32x4){0.f, 0.f, 0.f, 0.f};

  const short* wp[3];
#pragma unroll
  for (int nf = 0; nf < 3; ++nf)
    wp[nf] = wt + (size_t)(w * 48 + nf * 16 + q16) * DD + g * 8;

  const int srow_b = w * 16 + (lane >> 4);  // row for j=0; j adds 4
  const int ul = lane & 15;                 // linear 16B-unit within row

  bf16x8 bcur[3][2];
#pragma unroll
  for (int nf = 0; nf < 3; ++nf)
#pragma unroll
    for (int kf = 0; kf < 2; ++kf)
      bcur[nf][kf] = *(const bf16x8*)(wp[nf] + kf * 32);
#pragma unroll
  for (int t = 0; t < 3; ++t)
#pragma unroll
    for (int j = 0; j < 4; ++j) {
      const int row = srow_b + j * 4;
      const int us = ul ^ (row & 15);
      const float* src = x + (r0 + row) * DD + t * 64 + us * 4;
      __builtin_amdgcn_global_load_lds(
          (const __attribute__((address_space(1))) void*)src,
          (__attribute__((address_space(3))) void*)(&xls[t][0] + (w * 4 + j) * 256),
          16, 0, 0);
    }
  __builtin_amdgcn_sched_barrier(0);
  FENCE_VM(8);

  for (int ks = 0; ks < 16; ++ks) {
    const float* bufc = &xls[ks & 3][0];

    bf16x8 bnxt[3][2];
    if (ks < 15) {
      const int k1 = (ks + 1) << 6;
#pragma unroll
      for (int nf = 0; nf < 3; ++nf)
#pragma unroll
        for (int kf = 0; kf < 2; ++kf)
          bnxt[nf][kf] = *(const bf16x8*)(wp[nf] + k1 + kf * 32);
    }
    if (ks <= 12) {
#pragma unroll
      for (int j = 0; j < 4; ++j) {
        const int row = srow_b + j * 4;
        const int us = ul ^ (row & 15);
        const float* src = x + (r0 + row) * DD + (ks + 3) * 64 + us * 4;
        __builtin_amdgcn_global_load_lds(
            (const __attribute__((address_space(1))) void*)src,
            (__attribute__((address_space(3))) void*)(&xls[(ks + 3) & 3][0] +
                                                      (w * 4 + j) * 256),
            16, 0, 0);
      }
    }
    __builtin_amdgcn_sched_barrier(0);

    bf16x8 afr[4][2];
#pragma unroll
    for (int mf = 0; mf < 4; ++mf)
#pragma unroll
      for (int kf = 0; kf < 2; ++kf) {
        const int R = mf * 16 + q16;
        const int r15 = R & 15;
        const int u0 = kf * 8 + g * 2;
        const float4 fa = *(const float4*)(bufc + R * 64 + ((u0 ^ r15) << 2));
        const float4 fb = *(const float4*)(bufc + R * 64 + (((u0 + 1) ^ r15) << 2));
        unsigned* up = (unsigned*)&afr[mf][kf];
        up[0] = pk2(fa.x, fa.y);
        up[1] = pk2(fa.z, fa.w);
        up[2] = pk2(fb.x, fb.y);
        up[3] = pk2(fb.z, fb.w);
      }

#pragma unroll
    for (int mf = 0; mf < 4; ++mf)
#pragma unroll
      for (int nf = 0; nf < 3; ++nf)
#pragma unroll
        for (int kf = 0; kf < 2; ++kf)
          acc[mf][nf] = __builtin_amdgcn_mfma_f32_16x16x32_bf16(
              afr[mf][kf], bcur[nf][kf], acc[mf][nf], 0, 0, 0);

    if (ks < 15) {
      if (ks <= 12) FENCE_VM(14);
      else if (ks == 13) FENCE_VM(10);
      else FENCE_VM(6);
#pragma unroll
      for (int nf = 0; nf < 3; ++nf)
#pragma unroll
        for (int kf = 0; kf < 2; ++kf) bcur[nf][kf] = bnxt[nf][kf];
    }
  }

#pragma unroll
  for (int nf = 0; nf < 3; ++nf) {
    const int n = w * 48 + nf * 16 + q16;
    const int mat = n >> 6;
    const int h = n & 63;
    if (mat < 2) {
      short* outp = mat ? ko : qo;
      const float fac = mat ? 1.0f : QK_SCALE;
#pragma unroll
      for (int mf = 0; mf < 4; ++mf)
#pragma unroll
        for (int r = 0; r < 4; ++r)
          outp[(r0 + mf * 16 + g * 4 + r) * HH + h] = f2bf(acc[mf][nf][r] * fac);
    } else {
      const int bb = (int)(r0 >> 11);
      const int tloc = (int)(r0 & 2047);
#pragma unroll
      for (int mf = 0; mf < 4; ++mf) {
        uint2 pkv;
        pkv.x = pk2(acc[mf][nf][0], acc[mf][nf][1]);
        pkv.y = pk2(acc[mf][nf][2], acc[mf][nf][3]);
        *(uint2*)&vt[((size_t)bb * HH + h) * TT + tloc + mf * 16 + g * 4] = pkv;
      }
    }
  }
}

// ---------------------------------------------------------------------------
// Flash attention, SPLIT-K over key chunks (fixes R20's measured 13%
// occupancy tail). Grid 768 = 3 blocks/CU sustained:
//   wc = id>>4:  0..15  -> part0 of qt=31-wc  (chunks [0,ns0), no mask)
//                16..31 -> part1 of qt=31-(wc-16) (chunks [ns0,NC), mask)
//                32..47 -> single qt=47-wc    (full range, mask)
// part0 -> raw (po,m,l) to ws; part1 -> unnormalized po to out + (m,l) to
// ws; singles -> normal. attn_merge combines split tiles.
// ---------------------------------------------------------------------------
__global__ __launch_bounds__(256, 3) void attn_mfma(
    const short* __restrict__ q, const short* __restrict__ k,
    const short* __restrict__ vt, float* __restrict__ out,
    float* __restrict__ po0f, float* __restrict__ mlf) {
  __shared__ short klds[2][64 * 64];
  __shared__ short vlds[2][64 * 64];

  const int id = blockIdx.x;  // 0..767
  const int b = (id & 7) | (((id >> 3) & 1) << 3);
  const int wc = id >> 4;     // 0..47
  int qt, c0, c1, mode;       // 0=single, 1=part0, 2=part1
  if (wc < 16) {
    qt = 31 - wc; mode = 1; c0 = 0; c1 = (qt + 2) >> 1;
  } else if (wc < 32) {
    qt = 31 - (wc - 16); mode = 2; c0 = (qt + 2) >> 1; c1 = qt + 1;
  } else {
    qt = 47 - wc; mode = 0; c0 = 0; c1 = qt + 1;
  }
  const int t0 = qt << 6;
  const int tid = threadIdx.x;
  const int lane = tid & 63;
  const int w = tid >> 6;
  const int q16 = lane & 15;
  const int g = lane >> 4;

  const size_t brow = (size_t)b * TT;
  const short* kg = k + brow * HH;
  const short* vtg = vt + (size_t)b * HH * TT;

  const int srow = tid >> 2;
  const int scol = (tid & 3) << 4;

  const int vgA = (scol >> 3) & 3;
  const int vgB = ((scol + 8) >> 3) & 3;
  const int vm2 = scol >> 5;
  const short* vrow_p = vtg + srow * TT + vm2 * 32;

  const int s00 = c0 << 6;
  bf16x8 kr0 = *(const bf16x8*)&kg[(s00 + srow) * HH + scol];
  bf16x8 kr1 = *(const bf16x8*)&kg[(s00 + srow) * HH + scol + 8];
  bf16x4 va0 = *(const bf16x4*)(vrow_p + s00 + 4 * vgA);
  bf16x4 va1 = *(const bf16x4*)(vrow_p + s00 + 16 + 4 * vgA);
  bf16x4 vb0 = *(const bf16x4*)(vrow_p + s00 + 4 * vgB);
  bf16x4 vb1 = *(const bf16x4*)(vrow_p + s00 + 16 + 4 * vgB);

  {
    const short* qsrc = q + (brow + t0 + srow) * HH;
    *(bf16x8*)lds_swz(klds[0], srow, scol) = *(const bf16x8*)&qsrc[scol];
    *(bf16x8*)lds_swz(klds[0], srow, scol + 8) = *(const bf16x8*)&qsrc[scol + 8];
  }
  __syncthreads();
  bf16x8 qa[2];
#pragma unroll
  for (int kf = 0; kf < 2; ++kf)
    qa[kf] = *(bf16x8*)lds_swz(klds[0], w * 16 + q16, kf * 32 + g * 8);
  __syncthreads();

  *(bf16x8*)lds_swz(klds[0], srow, scol) = kr0;
  *(bf16x8*)lds_swz(klds[0], srow, scol + 8) = kr1;
  *(bf16x8*)lds_swz(vlds[0], srow, scol) =
      __builtin_shufflevector(va0, va1, 0, 1, 2, 3, 4, 5, 6, 7);
  *(bf16x8*)lds_swz(vlds[0], srow, scol + 8) =
      __builtin_shufflevector(vb0, vb1, 0, 1, 2, 3, 4, 5, 6, 7);
  __syncthreads();

  f32x4 po[4];
  f32x4 lacc = (f32x4){0.f, 0.f, 0.f, 0.f};
  float m = -INFINITY;
#pragma unroll
  for (int nf = 0; nf < 4; ++nf) po[nf] = (f32x4){0.f, 0.f, 0.f, 0.f};

  const bf16x8 ones = {0x3F80, 0x3F80, 0x3F80, 0x3F80,
                       0x3F80, 0x3F80, 0x3F80, 0x3F80};
  int cur = 0;

  for (int c = c0; c < c1; ++c) {
    const bool notlast = (c + 1 < c1);
    if (notlast) {
      const int s1 = (c + 1) << 6;
      kr0 = *(const bf16x8*)&kg[(s1 + srow) * HH + scol];
      kr1 = *(const bf16x8*)&kg[(s1 + srow) * HH + scol + 8];
      va0 = *(const bf16x4*)(vrow_p + s1 + 4 * vgA);
      va1 = *(const bf16x4*)(vrow_p + s1 + 16 + 4 * vgA);
      vb0 = *(const bf16x4*)(vrow_p + s1 + 4 * vgB);
      vb1 = *(const bf16x4*)(vrow_p + s1 + 16 + 4 * vgB);
    }

    f32x4 sfr[4];
#pragma unroll
    for (int nf = 0; nf < 4; ++nf) sfr[nf] = (f32x4){0.f, 0.f, 0.f, 0.f};
    __builtin_amdgcn_s_setprio(1);
#pragma unroll
    for (int nf = 0; nf < 4; ++nf)
#pragma unroll
      for (int kf = 0; kf < 2; ++kf) {
        bf16x8 kb = *(bf16x8*)lds_swz(klds[cur], nf * 16 + q16, kf * 32 + g * 8);
        sfr[nf] = __builtin_amdgcn_mfma_f32_16x16x32_bf16(kb, qa[kf], sfr[nf], 0, 0, 0);
      }
    __builtin_amdgcn_s_setprio(0);

    if (mode != 1 && c == c1 - 1) {  // diagonal chunk (single/part1 only)
      const int qloc = w * 16 + q16;
#pragma unroll
      for (int nf = 0; nf < 4; ++nf)
#pragma unroll
        for (int r = 0; r < 4; ++r)
          if (16 * nf + 4 * g + r > qloc) sfr[nf][r] = -INFINITY;
    }

    float pm;
    {
      f32x4 t01 = (f32x4){fmaxf(sfr[0][0], sfr[1][0]), fmaxf(sfr[0][1], sfr[1][1]),
                          fmaxf(sfr[0][2], sfr[1][2]), fmaxf(sfr[0][3], sfr[1][3])};
      f32x4 t23 = (f32x4){fmaxf(sfr[2][0], sfr[3][0]), fmaxf(sfr[2][1], sfr[3][1]),
                          fmaxf(sfr[2][2], sfr[3][2]), fmaxf(sfr[2][3], sfr[3][3])};
      pm = fmaxf(fmaxf(fmaxf(t01[0], t23[0]), fmaxf(t01[1], t23[1])),
                 fmaxf(fmaxf(t01[2], t23[2]), fmaxf(t01[3], t23[3])));
      pm = fmaxf(pm, __shfl_xor(pm, 16));
      pm = fmaxf(pm, __shfl_xor(pm, 32));
    }

    if (__any(pm - m > 8.f)) {
      const float mn = fmaxf(m, pm);
      const float corr = exp2f(m - mn);
      m = mn;
      const int sbase = (lane & 48) + ((lane >> 4) << 2);
#pragma unroll
      for (int r = 0; r < 4; ++r) {
        const float cr = __shfl(corr, sbase + r);
        lacc[r] *= cr;
#pragma unroll
        for (int nf = 0; nf < 4; ++nf) po[nf][r] *= cr;
      }
    }

    bf16x8 pa[2];
#pragma unroll
    for (int m2 = 0; m2 < 2; ++m2) {
      float e0 = exp2f(sfr[2 * m2][0] - m), e1 = exp2f(sfr[2 * m2][1] - m);
      float e2 = exp2f(sfr[2 * m2][2] - m), e3 = exp2f(sfr[2 * m2][3] - m);
      float e4 = exp2f(sfr[2 * m2 + 1][0] - m), e5 = exp2f(sfr[2 * m2 + 1][1] - m);
      float e6 = exp2f(sfr[2 * m2 + 1][2] - m), e7 = exp2f(sfr[2 * m2 + 1][3] - m);
      unsigned* up = (unsigned*)&pa[m2];
      up[0] = pk2(e0, e1); up[1] = pk2(e2, e3);
      up[2] = pk2(e4, e5); up[3] = pk2(e6, e7);
    }

    __builtin_amdgcn_s_setprio(1);
#pragma unroll
    for (int m2 = 0; m2 < 2; ++m2) {
#pragma unroll
      for (int nf = 0; nf < 4; ++nf) {
        bf16x8 vb = *(bf16x8*)lds_swz(vlds[cur], nf * 16 + q16, m2 * 32 + g * 8);
        po[nf] = __builtin_amdgcn_mfma_f32_16x16x32_bf16(pa[m2], vb, po[nf], 0, 0, 0);
      }
      lacc = __builtin_amdgcn_mfma_f32_16x16x32_bf16(pa[m2], ones, lacc, 0, 0, 0);
    }
    __builtin_amdgcn_s_setprio(0);

    if (notlast) {
      *(bf16x8*)lds_swz(klds[cur ^ 1], srow, scol) = kr0;
      *(bf16x8*)lds_swz(klds[cur ^ 1], srow, scol + 8) = kr1;
      *(bf16x8*)lds_swz(vlds[cur ^ 1], srow, scol) =
          __builtin_shufflevector(va0, va1, 0, 1, 2, 3, 4, 5, 6, 7);
      *(bf16x8*)lds_swz(vlds[cur ^ 1], srow, scol + 8) =
          __builtin_shufflevector(vb0, vb1, 0, 1, 2, 3, 4, 5, 6, 7);
      __syncthreads();
      cur ^= 1;
    }
  }

  if (mode == 0) {
    const int qrow = t0 + w * 16 + g * 4;
#pragma unroll
    for (int nf = 0; nf < 4; ++nf) {
      const int h = nf * 16 + q16;
#pragma unroll
      for (int r = 0; r < 4; ++r)
        out[(brow + qrow + r) * HH + h] = po[nf][r] / lacc[r];
    }
  } else {
    // raw partial: part0 -> ws tile, part1 -> out (unnormalized)
    float* dst = (mode == 1) ? (po0f + (size_t)((b << 4) + qt - 16) * 4096)
                             : (out + (brow + t0) * HH);
#pragma unroll
    for (int nf = 0; nf < 4; ++nf) {
      const int h = nf * 16 + q16;
#pragma unroll
      for (int r = 0; r < 4; ++r)
        dst[(w * 16 + 4 * g + r) * HH + h] = po[nf][r];
    }
    const int mlbase = ((b << 4) + qt - 16) * 64;
    float* mArr = mlf + ((mode == 1) ? 0 : 32768);
    float* lArr = mlf + ((mode == 1) ? 16384 : 49152);
    if (g == 0) mArr[mlbase + w * 16 + q16] = m;
    if (q16 == 0) {
#pragma unroll
      for (int r = 0; r < 4; ++r) lArr[mlbase + w * 16 + 4 * g + r] = lacc[r];
    }
  }
}

// ---------------------------------------------------------------------------
// Merge the two softmax partials for split tiles (qt >= 16).
// ---------------------------------------------------------------------------
__global__ __launch_bounds__(256) void attn_merge(
    const float* __restrict__ po0f, const float* __restrict__ mlf,
    float* __restrict__ out) {
  const int idx = blockIdx.x * 256 + threadIdx.x;  // 0..1048575
  const int bt = idx >> 12;        // (b<<4) + qti
  const int qh = idx & 4095;
  const int qq = qh >> 6;
  const int b = bt >> 4;
  const int qt = (bt & 15) + 16;
  const float m0 = mlf[bt * 64 + qq];
  const float l0 = mlf[16384 + bt * 64 + qq];
  const float m1 = mlf[32768 + bt * 64 + qq];
  const float l1 = mlf[49152 + bt * 64 + qq];
  const float p0 = po0f[idx];
  const size_t oidx = ((size_t)b * TT + (qt << 6) + qq) * HH + (qh & 63);
  const float p1 = out[oidx];
  const float ms = fmaxf(m0, m1);
  const float e0 = exp2f(m0 - ms);
  const float e1 = exp2f(m1 - ms);
  out[oidx] = (p0 * e0 + p1 * e1) / (l0 * e0 + l1 * e1);
}

extern "C" void kernel_launch(void* const* d_in, const int* in_sizes, int n_in,
                              void* d_out, int out_size, void* d_ws, size_t ws_size,
                              hipStream_t stream) {
  const float* x  = (const float*)d_in[0];
  const float* Wq = (const float*)d_in[1];
  const float* Wk = (const float*)d_in[2];
  const float* Wv = (const float*)d_in[3];
  float* out = (float*)d_out;

  const size_t bth = (size_t)BB * TT * HH;  // 2,097,152
  short* qb  = (short*)d_ws;
  short* kb  = qb + bth;
  short* vtb = kb + bth;
  short* wtb = vtb + bth;                   // 192*1024 shorts
  float* po0f = (float*)(wtb + 192 * 1024); // 1,048,576 floats (4 MB)
  float* mlf  = po0f + (size_t)1048576;     // 65,536 floats

  pack_wt<<<96, 256, 0, stream>>>(Wq, Wk, Wv, wtb);
  qkv_mfma<<<(BB * TT) / 64, 256, 0, stream>>>(x, wtb, qb, kb, vtb);
  attn_mfma<<<768, 256, 0, stream>>>(qb, kb, vtb, out, po0f, mlf);
  attn_merge<<<4096, 256, 0, stream>>>(po0f, mlf, out);
}

// Round 24
// 72.554 us; speedup vs baseline: 2.3647x; 1.0796x over previous
//
#include <hip/hip_runtime.h>
#include <hip/hip_bf16.h>
#include <math.h>

#define BB 16
#define TT 2048
#define DD 1024
#define HH 64
#define QK_SCALE 0.18033688011112042f  // 0.125 * log2(e)  (exp2-domain softmax)

typedef short bf16x8 __attribute__((ext_vector_type(8)));
typedef short bf16x4 __attribute__((ext_vector_type(4)));
typedef float f32x4 __attribute__((ext_vector_type(4)));

__device__ __forceinline__ short f2bf(float f) {  // RNE (cold paths only)
  union { float f; unsigned u; } c; c.f = f;
  unsigned u = c.u + 0x7FFFu + ((c.u >> 16) & 1u);
  return (short)(u >> 16);
}

// packed pair f32x2 -> bf16x2 (v_cvt_pk_bf16_f32 via standard cast API)
__device__ __forceinline__ unsigned pk2(float lo, float hi) {
  float2 t; t.x = lo; t.y = hi;
  __hip_bfloat162 h = __float22bfloat162_rn(t);
  union { __hip_bfloat162 h; unsigned u; } c; c.h = h;
  return c.u;
}

// Counted-vmcnt fences (T4)
#define FENCE_VM(N)                                        \
  do {                                                     \
    asm volatile("s_waitcnt vmcnt(" #N ")" ::: "memory");  \
    __builtin_amdgcn_sched_barrier(0);                     \
    __builtin_amdgcn_s_barrier();                          \
  } while (0)

// 64-col bf16 tile (128B row stride): XOR-swizzle 16B units by row&7.
__device__ __forceinline__ void* lds_swz(void* base, int row, int col) {
  int byte = (row << 7) + (col << 1);
  byte ^= (row & 7) << 4;
  return (void*)((char*)base + byte);
}

// ---------------------------------------------------------------------------
// Pack Wq|Wk|Wv (fp32 [D][H]) -> Wt bf16 K-OUTER layout [D/8][192][8]:
// element (n, k) lives at (k/8)*1536 + n*8 + (k%8). A wave's B-frag load
// (lanes q16 -> consecutive n, fixed k-group) is then 4 x 256B contiguous
// segments instead of 16 x 64B gathers -> 4x fewer L2 requests.
// ---------------------------------------------------------------------------
__global__ __launch_bounds__(256) void pack_wt(
    const float* __restrict__ Wq, const float* __restrict__ Wk,
    const float* __restrict__ Wv, short* __restrict__ wt) {
  const int idx = blockIdx.x * 256 + threadIdx.x;
  const int n = idx >> 7;                 // 0..191
  const int k0 = (idx & 127) << 3;        // 0..1016, multiple of 8
  const float* W = (n < 64) ? Wq : (n < 128) ? Wk : Wv;
  const int h = n & 63;
  bf16x8 o;
#pragma unroll
  for (int j = 0; j < 8; ++j) o[j] = f2bf(W[(k0 + j) * HH + h]);
  *(bf16x8*)&wt[(k0 >> 3) * 1536 + n * 8] = o;
}

// ---------------------------------------------------------------------------
// QKV GEMM (round-22/23 structure; ONLY change = k-outer W addressing).
// ---------------------------------------------------------------------------
__global__ __launch_bounds__(256, 2) void qkv_mfma(
    const float* __restrict__ x, const short* __restrict__ wt,
    short* __restrict__ qo, short* __restrict__ ko, short* __restrict__ vt) {
  __shared__ float xls[4][64 * 64];  // 4 x 16 KB fp32 tiles (64 KB)
  const int tid = threadIdx.x;
  const int lane = tid & 63;
  const int w = tid >> 6;
  const int q16 = lane & 15;
  const int g = lane >> 4;
  const size_t r0 = (size_t)blockIdx.x * 64;

  f32x4 acc[4][3];
#pragma unroll
  for (int mf = 0; mf < 4; ++mf)
#pragma unroll
    for (int nf = 0; nf < 3; ++nf) acc[mf][nf] = (f32x4){0.f, 0.f, 0.f, 0.f};

  // k-outer W base: lane reads 8 shorts at (k8)*1536 + n*8, k8 = ks*8+kf*4+g
  const short* wp[3];
#pragma unroll
  for (int nf = 0; nf < 3; ++nf)
    wp[nf] = wt + (size_t)g * 1536 + (size_t)(w * 48 + nf * 16 + q16) * 8;

  const int srow_b = w * 16 + (lane >> 4);  // row for j=0; j adds 4
  const int ul = lane & 15;                 // linear 16B-unit within row

  bf16x8 bcur[3][2];
#pragma unroll
  for (int nf = 0; nf < 3; ++nf)
#pragma unroll
    for (int kf = 0; kf < 2; ++kf)
      bcur[nf][kf] = *(const bf16x8*)(wp[nf] + kf * 4 * 1536);
#pragma unroll
  for (int t = 0; t < 3; ++t)
#pragma unroll
    for (int j = 0; j < 4; ++j) {
      const int row = srow_b + j * 4;
      const int us = ul ^ (row & 15);
      const float* src = x + (r0 + row) * DD + t * 64 + us * 4;
      __builtin_amdgcn_global_load_lds(
          (const __attribute__((address_space(1))) void*)src,
          (__attribute__((address_space(3))) void*)(&xls[t][0] + (w * 4 + j) * 256),
          16, 0, 0);
    }
  __builtin_amdgcn_sched_barrier(0);
  FENCE_VM(8);

  for (int ks = 0; ks < 16; ++ks) {
    const float* bufc = &xls[ks & 3][0];

    bf16x8 bnxt[3][2];
    if (ks < 15) {
      const int kb8 = (ks + 1) * 8 * 1536;
#pragma unroll
      for (int nf = 0; nf < 3; ++nf)
#pragma unroll
        for (int kf = 0; kf < 2; ++kf)
          bnxt[nf][kf] = *(const bf16x8*)(wp[nf] + kb8 + kf * 4 * 1536);
    }
    if (ks <= 12) {
#pragma unroll
      for (int j = 0; j < 4; ++j) {
        const int row = srow_b + j * 4;
        const int us = ul ^ (row & 15);
        const float* src = x + (r0 + row) * DD + (ks + 3) * 64 + us * 4;
        __builtin_amdgcn_global_load_lds(
            (const __attribute__((address_space(1))) void*)src,
            (__attribute__((address_space(3))) void*)(&xls[(ks + 3) & 3][0] +
                                                      (w * 4 + j) * 256),
            16, 0, 0);
      }
    }
    __builtin_amdgcn_sched_barrier(0);

    bf16x8 afr[4][2];
#pragma unroll
    for (int mf = 0; mf < 4; ++mf)
#pragma unroll
      for (int kf = 0; kf < 2; ++kf) {
        const int R = mf * 16 + q16;
        const int r15 = R & 15;
        const int u0 = kf * 8 + g * 2;
        const float4 fa = *(const float4*)(bufc + R * 64 + ((u0 ^ r15) << 2));
        const float4 fb = *(const float4*)(bufc + R * 64 + (((u0 + 1) ^ r15) << 2));
        unsigned* up = (unsigned*)&afr[mf][kf];
        up[0] = pk2(fa.x, fa.y);
        up[1] = pk2(fa.z, fa.w);
        up[2] = pk2(fb.x, fb.y);
        up[3] = pk2(fb.z, fb.w);
      }

#pragma unroll
    for (int mf = 0; mf < 4; ++mf)
#pragma unroll
      for (int nf = 0; nf < 3; ++nf)
#pragma unroll
        for (int kf = 0; kf < 2; ++kf)
          acc[mf][nf] = __builtin_amdgcn_mfma_f32_16x16x32_bf16(
              afr[mf][kf], bcur[nf][kf], acc[mf][nf], 0, 0, 0);

    if (ks < 15) {
      if (ks <= 12) FENCE_VM(14);
      else if (ks == 13) FENCE_VM(10);
      else FENCE_VM(6);
#pragma unroll
      for (int nf = 0; nf < 3; ++nf)
#pragma unroll
        for (int kf = 0; kf < 2; ++kf) bcur[nf][kf] = bnxt[nf][kf];
    }
  }

#pragma unroll
  for (int nf = 0; nf < 3; ++nf) {
    const int n = w * 48 + nf * 16 + q16;
    const int mat = n >> 6;
    const int h = n & 63;
    if (mat < 2) {
      short* outp = mat ? ko : qo;
      const float fac = mat ? 1.0f : QK_SCALE;
#pragma unroll
      for (int mf = 0; mf < 4; ++mf)
#pragma unroll
        for (int r = 0; r < 4; ++r)
          outp[(r0 + mf * 16 + g * 4 + r) * HH + h] = f2bf(acc[mf][nf][r] * fac);
    } else {
      const int bb = (int)(r0 >> 11);
      const int tloc = (int)(r0 & 2047);
#pragma unroll
      for (int mf = 0; mf < 4; ++mf) {
        uint2 pkv;
        pkv.x = pk2(acc[mf][nf][0], acc[mf][nf][1]);
        pkv.y = pk2(acc[mf][nf][2], acc[mf][nf][3]);
        *(uint2*)&vt[((size_t)bb * HH + h) * TT + tloc + mf * 16 + g * 4] = pkv;
      }
    }
  }
}

// ---------------------------------------------------------------------------
// Flash attention, split-K over key chunks (round-23, unchanged).
// ---------------------------------------------------------------------------
__global__ __launch_bounds__(256, 3) void attn_mfma(
    const short* __restrict__ q, const short* __restrict__ k,
    const short* __restrict__ vt, float* __restrict__ out,
    float* __restrict__ po0f, float* __restrict__ mlf) {
  __shared__ short klds[2][64 * 64];
  __shared__ short vlds[2][64 * 64];

  const int id = blockIdx.x;  // 0..767
  const int b = (id & 7) | (((id >> 3) & 1) << 3);
  const int wc = id >> 4;     // 0..47
  int qt, c0, c1, mode;       // 0=single, 1=part0, 2=part1
  if (wc < 16) {
    qt = 31 - wc; mode = 1; c0 = 0; c1 = (qt + 2) >> 1;
  } else if (wc < 32) {
    qt = 31 - (wc - 16); mode = 2; c0 = (qt + 2) >> 1; c1 = qt + 1;
  } else {
    qt = 47 - wc; mode = 0; c0 = 0; c1 = qt + 1;
  }
  const int t0 = qt << 6;
  const int tid = threadIdx.x;
  const int lane = tid & 63;
  const int w = tid >> 6;
  const int q16 = lane & 15;
  const int g = lane >> 4;

  const size_t brow = (size_t)b * TT;
  const short* kg = k + brow * HH;
  const short* vtg = vt + (size_t)b * HH * TT;

  const int srow = tid >> 2;
  const int scol = (tid & 3) << 4;

  const int vgA = (scol >> 3) & 3;
  const int vgB = ((scol + 8) >> 3) & 3;
  const int vm2 = scol >> 5;
  const short* vrow_p = vtg + srow * TT + vm2 * 32;

  const int s00 = c0 << 6;
  bf16x8 kr0 = *(const bf16x8*)&kg[(s00 + srow) * HH + scol];
  bf16x8 kr1 = *(const bf16x8*)&kg[(s00 + srow) * HH + scol + 8];
  bf16x4 va0 = *(const bf16x4*)(vrow_p + s00 + 4 * vgA);
  bf16x4 va1 = *(const bf16x4*)(vrow_p + s00 + 16 + 4 * vgA);
  bf16x4 vb0 = *(const bf16x4*)(vrow_p + s00 + 4 * vgB);
  bf16x4 vb1 = *(const bf16x4*)(vrow_p + s00 + 16 + 4 * vgB);

  {
    const short* qsrc = q + (brow + t0 + srow) * HH;
    *(bf16x8*)lds_swz(klds[0], srow, scol) = *(const bf16x8*)&qsrc[scol];
    *(bf16x8*)lds_swz(klds[0], srow, scol + 8) = *(const bf16x8*)&qsrc[scol + 8];
  }
  __syncthreads();
  bf16x8 qa[2];
#pragma unroll
  for (int kf = 0; kf < 2; ++kf)
    qa[kf] = *(bf16x8*)lds_swz(klds[0], w * 16 + q16, kf * 32 + g * 8);
  __syncthreads();

  *(bf16x8*)lds_swz(klds[0], srow, scol) = kr0;
  *(bf16x8*)lds_swz(klds[0], srow, scol + 8) = kr1;
  *(bf16x8*)lds_swz(vlds[0], srow, scol) =
      __builtin_shufflevector(va0, va1, 0, 1, 2, 3, 4, 5, 6, 7);
  *(bf16x8*)lds_swz(vlds[0], srow, scol + 8) =
      __builtin_shufflevector(vb0, vb1, 0, 1, 2, 3, 4, 5, 6, 7);
  __syncthreads();

  f32x4 po[4];
  f32x4 lacc = (f32x4){0.f, 0.f, 0.f, 0.f};
  float m = -INFINITY;
#pragma unroll
  for (int nf = 0; nf < 4; ++nf) po[nf] = (f32x4){0.f, 0.f, 0.f, 0.f};

  const bf16x8 ones = {0x3F80, 0x3F80, 0x3F80, 0x3F80,
                       0x3F80, 0x3F80, 0x3F80, 0x3F80};
  int cur = 0;

  for (int c = c0; c < c1; ++c) {
    const bool notlast = (c + 1 < c1);
    if (notlast) {
      const int s1 = (c + 1) << 6;
      kr0 = *(const bf16x8*)&kg[(s1 + srow) * HH + scol];
      kr1 = *(const bf16x8*)&kg[(s1 + srow) * HH + scol + 8];
      va0 = *(const bf16x4*)(vrow_p + s1 + 4 * vgA);
      va1 = *(const bf16x4*)(vrow_p + s1 + 16 + 4 * vgA);
      vb0 = *(const bf16x4*)(vrow_p + s1 + 4 * vgB);
      vb1 = *(const bf16x4*)(vrow_p + s1 + 16 + 4 * vgB);
    }

    f32x4 sfr[4];
#pragma unroll
    for (int nf = 0; nf < 4; ++nf) sfr[nf] = (f32x4){0.f, 0.f, 0.f, 0.f};
    __builtin_amdgcn_s_setprio(1);
#pragma unroll
    for (int nf = 0; nf < 4; ++nf)
#pragma unroll
      for (int kf = 0; kf < 2; ++kf) {
        bf16x8 kb = *(bf16x8*)lds_swz(klds[cur], nf * 16 + q16, kf * 32 + g * 8);
        sfr[nf] = __builtin_amdgcn_mfma_f32_16x16x32_bf16(kb, qa[kf], sfr[nf], 0, 0, 0);
      }
    __builtin_amdgcn_s_setprio(0);

    if (mode != 1 && c == c1 - 1) {  // diagonal chunk (single/part1 only)
      const int qloc = w * 16 + q16;
#pragma unroll
      for (int nf = 0; nf < 4; ++nf)
#pragma unroll
        for (int r = 0; r < 4; ++r)
          if (16 * nf + 4 * g + r > qloc) sfr[nf][r] = -INFINITY;
    }

    float pm;
    {
      f32x4 t01 = (f32x4){fmaxf(sfr[0][0], sfr[1][0]), fmaxf(sfr[0][1], sfr[1][1]),
                          fmaxf(sfr[0][2], sfr[1][2]), fmaxf(sfr[0][3], sfr[1][3])};
      f32x4 t23 = (f32x4){fmaxf(sfr[2][0], sfr[3][0]), fmaxf(sfr[2][1], sfr[3][1]),
                          fmaxf(sfr[2][2], sfr[3][2]), fmaxf(sfr[2][3], sfr[3][3])};
      pm = fmaxf(fmaxf(fmaxf(t01[0], t23[0]), fmaxf(t01[1], t23[1])),
                 fmaxf(fmaxf(t01[2], t23[2]), fmaxf(t01[3], t23[3])));
      pm = fmaxf(pm, __shfl_xor(pm, 16));
      pm = fmaxf(pm, __shfl_xor(pm, 32));
    }

    if (__any(pm - m > 8.f)) {
      const float mn = fmaxf(m, pm);
      const float corr = exp2f(m - mn);
      m = mn;
      const int sbase = (lane & 48) + ((lane >> 4) << 2);
#pragma unroll
      for (int r = 0; r < 4; ++r) {
        const float cr = __shfl(corr, sbase + r);
        lacc[r] *= cr;
#pragma unroll
        for (int nf = 0; nf < 4; ++nf) po[nf][r] *= cr;
      }
    }

    bf16x8 pa[2];
#pragma unroll
    for (int m2 = 0; m2 < 2; ++m2) {
      float e0 = exp2f(sfr[2 * m2][0] - m), e1 = exp2f(sfr[2 * m2][1] - m);
      float e2 = exp2f(sfr[2 * m2][2] - m), e3 = exp2f(sfr[2 * m2][3] - m);
      float e4 = exp2f(sfr[2 * m2 + 1][0] - m), e5 = exp2f(sfr[2 * m2 + 1][1] - m);
      float e6 = exp2f(sfr[2 * m2 + 1][2] - m), e7 = exp2f(sfr[2 * m2 + 1][3] - m);
      unsigned* up = (unsigned*)&pa[m2];
      up[0] = pk2(e0, e1); up[1] = pk2(e2, e3);
      up[2] = pk2(e4, e5); up[3] = pk2(e6, e7);
    }

    __builtin_amdgcn_s_setprio(1);
#pragma unroll
    for (int m2 = 0; m2 < 2; ++m2) {
#pragma unroll
      for (int nf = 0; nf < 4; ++nf) {
        bf16x8 vb = *(bf16x8*)lds_swz(vlds[cur], nf * 16 + q16, m2 * 32 + g * 8);
        po[nf] = __builtin_amdgcn_mfma_f32_16x16x32_bf16(pa[m2], vb, po[nf], 0, 0, 0);
      }
      lacc = __builtin_amdgcn_mfma_f32_16x16x32_bf16(pa[m2], ones, lacc, 0, 0, 0);
    }
    __builtin_amdgcn_s_setprio(0);

    if (notlast) {
      *(bf16x8*)lds_swz(klds[cur ^ 1], srow, scol) = kr0;
      *(bf16x8*)lds_swz(klds[cur ^ 1], srow, scol + 8) = kr1;
      *(bf16x8*)lds_swz(vlds[cur ^ 1], srow, scol) =
          __builtin_shufflevector(va0, va1, 0, 1, 2, 3, 4, 5, 6, 7);
      *(bf16x8*)lds_swz(vlds[cur ^ 1], srow, scol + 8) =
          __builtin_shufflevector(vb0, vb1, 0, 1, 2, 3, 4, 5, 6, 7);
      __syncthreads();
      cur ^= 1;
    }
  }

  if (mode == 0) {
    const int qrow = t0 + w * 16 + g * 4;
#pragma unroll
    for (int nf = 0; nf < 4; ++nf) {
      const int h = nf * 16 + q16;
#pragma unroll
      for (int r = 0; r < 4; ++r)
        out[(brow + qrow + r) * HH + h] = po[nf][r] / lacc[r];
    }
  } else {
    float* dst = (mode == 1) ? (po0f + (size_t)((b << 4) + qt - 16) * 4096)
                             : (out + (brow + t0) * HH);
#pragma unroll
    for (int nf = 0; nf < 4; ++nf) {
      const int h = nf * 16 + q16;
#pragma unroll
      for (int r = 0; r < 4; ++r)
        dst[(w * 16 + 4 * g + r) * HH + h] = po[nf][r];
    }
    const int mlbase = ((b << 4) + qt - 16) * 64;
    float* mArr = mlf + ((mode == 1) ? 0 : 32768);
    float* lArr = mlf + ((mode == 1) ? 16384 : 49152);
    if (g == 0) mArr[mlbase + w * 16 + q16] = m;
    if (q16 == 0) {
#pragma unroll
      for (int r = 0; r < 4; ++r) lArr[mlbase + w * 16 + 4 * g + r] = lacc[r];
    }
  }
}

// ---------------------------------------------------------------------------
// Merge the two softmax partials for split tiles (qt >= 16).
// ---------------------------------------------------------------------------
__global__ __launch_bounds__(256) void attn_merge(
    const float* __restrict__ po0f, const float* __restrict__ mlf,
    float* __restrict__ out) {
  const int idx = blockIdx.x * 256 + threadIdx.x;  // 0..1048575
  const int bt = idx >> 12;        // (b<<4) + qti
  const int qh = idx & 4095;
  const int qq = qh >> 6;
  const int b = bt >> 4;
  const int qt = (bt & 15) + 16;
  const float m0 = mlf[bt * 64 + qq];
  const float l0 = mlf[16384 + bt * 64 + qq];
  const float m1 = mlf[32768 + bt * 64 + qq];
  const float l1 = mlf[49152 + bt * 64 + qq];
  const float p0 = po0f[idx];
  const size_t oidx = ((size_t)b * TT + (qt << 6) + qq) * HH + (qh & 63);
  const float p1 = out[oidx];
  const float ms = fmaxf(m0, m1);
  const float e0 = exp2f(m0 - ms);
  const float e1 = exp2f(m1 - ms);
  out[oidx] = (p0 * e0 + p1 * e1) / (l0 * e0 + l1 * e1);
}

extern "C" void kernel_launch(void* const* d_in, const int* in_sizes, int n_in,
                              void* d_out, int out_size, void* d_ws, size_t ws_size,
                              hipStream_t stream) {
  const float* x  = (const float*)d_in[0];
  const float* Wq = (const float*)d_in[1];
  const float* Wk = (const float*)d_in[2];
  const float* Wv = (const float*)d_in[3];
  float* out = (float*)d_out;

  const size_t bth = (size_t)BB * TT * HH;  // 2,097,152
  short* qb  = (short*)d_ws;
  short* kb  = qb + bth;
  short* vtb = kb + bth;
  short* wtb = vtb + bth;                   // 192*1024 shorts (k-outer)
  float* po0f = (float*)(wtb + 192 * 1024); // 1,048,576 floats (4 MB)
  float* mlf  = po0f + (size_t)1048576;     // 65,536 floats

  pack_wt<<<96, 256, 0, stream>>>(Wq, Wk, Wv, wtb);
  qkv_mfma<<<(BB * TT) / 64, 256, 0, stream>>>(x, wtb, qb, kb, vtb);
  attn_mfma<<<768, 256, 0, stream>>>(qb, kb, vtb, out, po0f, mlf);
  attn_merge<<<4096, 256, 0, stream>>>(po0f, mlf, out);
}